// Round 9
// baseline (784.694 us; speedup 1.0000x reference)
//
#include <hip/hip_runtime.h>
#include <hip/hip_bf16.h>
#include <cstddef>

using u16 = unsigned short;
using short8 = __attribute__((ext_vector_type(8))) short;
using f32x4 = __attribute__((ext_vector_type(4))) float;

constexpr int B_   = 8192;
constexpr int IN_  = 256;
constexpr int COND_= 1024;
constexpr int H_   = 1024;
constexpr int LAT_ = 128;
constexpr int NE_  = 6;
constexpr int GH_  = 64;
constexpr int INP_ = 1152;   // LAT+COND == LAT+H
constexpr int K0_  = 1536;   // IN+COND+IN
constexpr int K1_  = 1280;   // H+IN

constexpr int BK = 64;       // K-step (128 B per LDS row)

typedef const __attribute__((address_space(1))) void gv_t;
typedef __attribute__((address_space(3))) void lv_t;
#define GLDS(g, l) __builtin_amdgcn_global_load_lds((gv_t*)(g), (lv_t*)(l), 16, 0, 0)

__device__ __forceinline__ u16 f2b(float f) {
  __hip_bfloat16 h = __float2bfloat16(f);
  return *reinterpret_cast<u16*>(&h);
}
__device__ __forceinline__ float elu1(float x) { return x > 0.f ? x : (__expf(x) - 1.f); }

// ---------------- transpose + f32->bf16 convert (used for ew1T only)
__global__ void k_transpose(const float* __restrict__ in, u16* __restrict__ out,
                            int R, int C, long inStride, long outStride) {
  __shared__ float t[32][33];
  const float* ip = in + (long)blockIdx.z * inStride;
  u16* op = out + (long)blockIdx.z * outStride;
  int c0 = blockIdx.x * 32, r0 = blockIdx.y * 32;
  int tx = threadIdx.x, ty = threadIdx.y; // 32x8
#pragma unroll
  for (int i = 0; i < 4; i++) {
    int r = r0 + ty + i * 8, c = c0 + tx;
    if (r < R && c < C) t[ty + i * 8][tx] = ip[(long)r * C + c];
  }
  __syncthreads();
#pragma unroll
  for (int i = 0; i < 4; i++) {
    int c = c0 + ty + i * 8, r = r0 + tx;
    if (r < R && c < C) op[(long)c * R + r] = f2b(t[tx][ty + i * 8]);
  }
}

// ---------------- k_pre: ALL upfront weight transposes + A0/A1 concat prep.
__global__ __launch_bounds__(256) void k_pre(
    const float* __restrict__ enc_w0, const float* __restrict__ enc_w1,
    const float* __restrict__ mu_w, const float* __restrict__ lv_w,
    const float* __restrict__ g_w0, const float* __restrict__ exp_w0,
    const float* __restrict__ x, const float* __restrict__ y,
    u16* __restrict__ encw0T, u16* __restrict__ encw1T, u16* __restrict__ mulvT,
    u16* __restrict__ gw0T, u16* __restrict__ ew0T,
    u16* __restrict__ A0, u16* __restrict__ A1)
{
  __shared__ float t[32][33];
  const int b = blockIdx.x;
  const int tid = threadIdx.x;
  const int tx = tid & 31, ty = tid >> 5;

  auto tr = [&](const float* in, u16* out, int R, int C, int bx, int by) {
    int c0 = bx * 32, r0 = by * 32;
#pragma unroll
    for (int i = 0; i < 4; i++) {
      int r = r0 + ty + i * 8, c = c0 + tx;
      if (r < R && c < C) t[ty + i * 8][tx] = in[(long)r * C + c];
    }
    __syncthreads();
#pragma unroll
    for (int i = 0; i < 4; i++) {
      int c = c0 + ty + i * 8, r = r0 + tx;
      if (r < R && c < C) out[(long)c * R + r] = f2b(t[tx][ty + i * 8]);
    }
  };

  if (b < 1536)       { tr(enc_w0, encw0T, K0_, H_, b & 31, b >> 5); }
  else if (b < 2816)  { int l = b - 1536; tr(enc_w1, encw1T, K1_, H_, l & 31, l >> 5); }
  else if (b < 2944)  { int l = b - 2816; tr(mu_w, mulvT, H_, LAT_, l & 3, l >> 2); }
  else if (b < 3072)  { int l = b - 2944; tr(lv_w, mulvT + (size_t)LAT_ * H_, H_, LAT_, l & 3, l >> 2); }
  else if (b < 3144)  { int l = b - 3072; tr(g_w0, gw0T, INP_, GH_, l & 1, l >> 1); }
  else if (b < 10056) {
    int l = b - 3144, e = l / 1152, r2 = l % 1152;
    tr(exp_w0 + (long)e * INP_ * H_, ew0T + (long)e * INP_ * H_, INP_, H_, r2 & 31, r2 >> 5);
  } else {
    long idx = (long)(b - 10056) * 256 + tid;
    long n0 = (long)B_ * K0_;
    if (idx < n0) {
      int bb = (int)(idx / K0_), c = (int)(idx % K0_);
      float v;
      if (c < IN_)              v = x[(long)bb * IN_ + c];
      else if (c < IN_ + COND_) v = y[(long)bb * COND_ + (c - IN_)];
      else                      v = x[(long)bb * IN_ + (c - IN_ - COND_)];
      A0[idx] = f2b(v);
    } else {
      long j = idx - n0;
      if (j < (long)B_ * IN_) {
        int bb = (int)(j / IN_), c = (int)(j % IN_);
        A1[(long)bb * K1_ + H_ + c] = f2b(x[(long)bb * IN_ + c]);
      }
    }
  }
}

// ---------------- k_mid: exp_w2 transpose (blocks [0,1728)) + z/ZY/D1/D2 fill
__global__ __launch_bounds__(256) void k_mid(
    const float* __restrict__ exp_w2, u16* __restrict__ ew2T,
    const float* __restrict__ mu, const float* __restrict__ lv,
    const float* __restrict__ eps, const float* __restrict__ y,
    u16* __restrict__ ZY, u16* __restrict__ D1, u16* __restrict__ D2)
{
  __shared__ float t[32][33];
  const int b = blockIdx.x;
  const int tid = threadIdx.x;
  if (b < 1728) {
    const int tx = tid & 31, ty = tid >> 5;
    int e = b / 288, r2 = b % 288;
    const float* in = exp_w2 + (long)e * INP_ * IN_;
    u16* out = ew2T + (long)e * INP_ * IN_;
    int c0 = (r2 & 7) * 32, r0 = (r2 >> 3) * 32;
#pragma unroll
    for (int i = 0; i < 4; i++) {
      int r = r0 + ty + i * 8, c = c0 + tx;
      if (r < INP_ && c < IN_) t[ty + i * 8][tx] = in[(long)r * IN_ + c];
    }
    __syncthreads();
#pragma unroll
    for (int i = 0; i < 4; i++) {
      int c = c0 + ty + i * 8, r = r0 + tx;
      if (r < INP_ && c < IN_) out[(long)c * INP_ + r] = f2b(t[tx][ty + i * 8]);
    }
  } else {
    long idx = (long)(b - 1728) * 256 + tid;
    if (idx >= (long)B_ * INP_) return;
    int bb = (int)(idx / INP_), c = (int)(idx % INP_);
    if (c < LAT_) {
      long o = (long)bb * LAT_ + c;
      float z = mu[o] + eps[o] * __expf(0.5f * lv[o]);
      u16 zb = f2b(z);
      ZY[idx] = zb; D1[idx] = zb; D2[idx] = zb;
    } else {
      ZY[idx] = f2b(y[(long)bb * COND_ + (c - LAT_)]);
    }
  }
}

// ---------------- gating tail
__global__ __launch_bounds__(256) void k_gate(const float* __restrict__ G1,
    const float* __restrict__ w1, const float* __restrict__ b1,
    const float* __restrict__ w2, const float* __restrict__ b2,
    float* __restrict__ coeff) {
  __shared__ float W1[64][65];
  __shared__ float W2[64][8];
  __shared__ float B1[64], B2[8];
  int tid = threadIdx.x;
  for (int i = tid; i < 64 * 64; i += 256) W1[i >> 6][i & 63] = w1[i];
  for (int i = tid; i < 64 * 6; i += 256) W2[i / 6][i % 6] = w2[i];
  if (tid < 64) B1[tid] = b1[tid];
  if (tid < 8)  B2[tid] = (tid < 6) ? b2[tid] : 0.f;
  __syncthreads();
  int row = blockIdx.x * 256 + tid;
  const float* gr = G1 + (long)row * GH_;
  float g[64];
#pragma unroll
  for (int i = 0; i < 16; i++) {
    float4 v = *(const float4*)(gr + i * 4);
    g[i*4] = v.x; g[i*4+1] = v.y; g[i*4+2] = v.z; g[i*4+3] = v.w;
  }
  float lg[6];
#pragma unroll
  for (int e = 0; e < 6; e++) lg[e] = B2[e];
  for (int n = 0; n < 64; n++) {
    float s = B1[n];
#pragma unroll
    for (int k = 0; k < 64; k++) s += g[k] * W1[k][n];
    s = elu1(s);
#pragma unroll
    for (int e = 0; e < 6; e++) lg[e] += s * W2[n][e];
  }
  float m = lg[0];
#pragma unroll
  for (int e = 1; e < 6; e++) m = fmaxf(m, lg[e]);
  float p[6], sum = 0.f;
#pragma unroll
  for (int e = 0; e < 6; e++) { p[e] = __expf(lg[e] - m); sum += p[e]; }
  float inv = 1.f / sum;
#pragma unroll
  for (int e = 0; e < 6; e++) coeff[(long)row * 6 + e] = p[e] * inv;
}

// ================= k_moe8: kt-outer / expert-inner MoE GEMM. BM=256, BN=128.
// A[kt] staged ONCE per kt (ring-2), fragments HELD IN REGISTERS across all 6
// expert steps; B[e][kt] streams (ring-3). Eager per-step merge: pacc is
// per-(kt,e) transient (phase0 MFMA takes zero C), acc += c_e*pacc after each
// step. CfT[6][256] transposed coeffs -> 4 broadcast ds_read_b128 per step.
// Counted vmcnt per 6-step group: W=[2,2,6,6,2,2] (B-then-A issue at g==2).
template<int KSTEPS>
__global__ __launch_bounds__(512, 2) void k_moe8(
    const u16* __restrict__ A,
    const u16* __restrict__ WT,
    const float* __restrict__ bias,     // [6][N]
    const float* __restrict__ coeff,    // [M][6]
    int N,
    u16* __restrict__ outH, int ldo)
{
  constexpr int KK = KSTEPS * BK;
  __shared__ __align__(16) u16 As[2][256][BK];
  __shared__ __align__(16) u16 Bs[3][128][BK];
  __shared__ float CfT[6][256];

  const int tid = threadIdx.x;
  const int lane = tid & 63, w = tid >> 6;       // 8 waves
  const int wr = w >> 1, wc = w & 1;             // 4 x 2
  const int lin = blockIdx.x + blockIdx.y * gridDim.x;
  const int rb  = (lin & 7) * 4 + ((lin >> 3) & 3);  // row-slab XCD swizzle
  const int cp  = lin >> 5;
  const int brow = rb * 256, bcol = cp * 128;
  const int lr = lane & 15, hi = lane >> 4;
  const int lk = hi * 8;
  const int xsw = (lr & 7) << 3;

  if (tid < 256) {
#pragma unroll
    for (int e = 0; e < 6; e++) CfT[e][tid] = coeff[(long)(brow + tid) * 6 + e];
  }
  __syncthreads();   // CfT visible; drains its loads before vmcnt counting

  f32x4 acc[4][4];
#pragma unroll
  for (int m = 0; m < 4; m++)
#pragma unroll
    for (int n = 0; n < 4; n++)
#pragma unroll
      for (int r = 0; r < 4; r++) acc[m][n][r] = 0.f;
  const f32x4 zf = {0.f, 0.f, 0.f, 0.f};
  f32x4 pacc[4][4];

  const int srow = w * 8 + (lane >> 3);
  const int sdst = (lane & 7) * 8;
  const int ssrc = ((lane & 7) ^ ((lane >> 3) & 7)) * 8;
  const u16* Asrc = A + (long)(brow + srow) * KK + ssrc;
  const u16* Bsrc = WT + (long)(bcol + srow) * KK + ssrc;

  auto STAGE_A = [&](int kt2, int abuf2) {       // 4 GLDS
    const u16* ap = Asrc + (long)kt2 * BK;
#pragma unroll
    for (int i = 0; i < 4; i++)
      GLDS(ap + (long)(i * 64) * KK, &As[abuf2][i * 64 + srow][sdst]);
  };
  auto STAGE_B = [&](int e2, int k2, int buf) {  // 2 GLDS
    const u16* bp = Bsrc + (long)e2 * ((long)N * KK) + (long)k2 * BK;
    GLDS(bp,                 &Bs[buf][srow][sdst]);
    GLDS(bp + (long)64 * KK, &Bs[buf][64 + srow][sdst]);
  };

  // prologue: A[0], B[e=0,kt=0], B[e=1,kt=0]; drain A+B0, keep B1 in flight
  STAGE_A(0, 0);
  STAGE_B(0, 0, 0);
  STAGE_B(1, 0, 1);
  asm volatile("s_waitcnt vmcnt(2)" ::: "memory");
  asm volatile("s_barrier" ::: "memory");

  short8 af[2][4];   // A fragments for both phases, held across 6 expert steps

  for (int kt = 0; kt < KSTEPS; ++kt) {
    const int abuf = kt & 1;
    const bool haveA = (kt + 1 < KSTEPS);
#pragma unroll
    for (int g = 0; g < 6; ++g) {              // g == expert index
      const int cur = g % 3;                   // (kt*6+g)%3 == g%3
      const int nbuf = (g + 2) % 3;
      const int e2 = (g + 2) % 6;              // staged step s+2 -> expert
      const int k2 = kt + (g >= 4 ? 1 : 0);    //                 -> K-chunk
      const bool stageB = (k2 < KSTEPS);

      float4 cg[4];
      { // ---------- phase 0 (kk = 0) ----------
        if (g == 0) {
#pragma unroll
          for (int p = 0; p < 2; p++)
#pragma unroll
            for (int m = 0; m < 4; m++)
              af[p][m] = *(const short8*)&As[abuf][wr * 64 + m * 16 + lr][(p * 32 + lk) ^ xsw];
        }
#pragma unroll
        for (int m = 0; m < 4; m++)            // broadcast reads (16 lanes/addr)
          cg[m] = *(const float4*)&CfT[g][wr * 64 + m * 16 + hi * 4];
        short8 bfr[4];
        const int cc0 = lk ^ xsw;
#pragma unroll
        for (int n = 0; n < 4; n++)
          bfr[n] = *(const short8*)&Bs[cur][wc * 64 + n * 16 + lr][cc0];
        if (stageB) STAGE_B(e2, k2, nbuf);
        if (g == 2 && haveA) STAGE_A(kt + 1, abuf ^ 1);
        asm volatile("s_barrier" ::: "memory");
        __builtin_amdgcn_s_setprio(1);
#pragma unroll
        for (int m = 0; m < 4; m++)
#pragma unroll
          for (int n = 0; n < 4; n++)
            pacc[m][n] = __builtin_amdgcn_mfma_f32_16x16x32_bf16(af[0][m], bfr[n], zf, 0, 0, 0);
        __builtin_amdgcn_s_setprio(0);
        asm volatile("s_barrier" ::: "memory");
      }
      { // ---------- phase 1 (kk = 32) ----------
        short8 bfr[4];
        const int cc1 = (32 + lk) ^ xsw;
#pragma unroll
        for (int n = 0; n < 4; n++)
          bfr[n] = *(const short8*)&Bs[cur][wc * 64 + n * 16 + lr][cc1];
        asm volatile("s_barrier" ::: "memory");
        __builtin_amdgcn_s_setprio(1);
#pragma unroll
        for (int m = 0; m < 4; m++)
#pragma unroll
          for (int n = 0; n < 4; n++)
            pacc[m][n] = __builtin_amdgcn_mfma_f32_16x16x32_bf16(af[1][m], bfr[n], pacc[m][n], 0, 0, 0);
        __builtin_amdgcn_s_setprio(0);
        // end-of-step wait: B[s+1] landed; newer loads stay in flight
        if (stageB) {
          if ((g == 2 || g == 3) && haveA)
            asm volatile("s_waitcnt vmcnt(6)" ::: "memory");
          else
            asm volatile("s_waitcnt vmcnt(2)" ::: "memory");
        } else if (g == 4) {
          asm volatile("s_waitcnt vmcnt(0)" ::: "memory");
        }
        asm volatile("s_barrier" ::: "memory");
      }
      // ---------- eager merge: acc += c_g * pacc ----------
#pragma unroll
      for (int m = 0; m < 4; m++)
#pragma unroll
        for (int r = 0; r < 4; r++) {
          const float c = cg[m][r];
#pragma unroll
          for (int n = 0; n < 4; n++) acc[m][n][r] += c * pacc[m][n][r];
        }
    }
  }

  // epilogue
#pragma unroll
  for (int m = 0; m < 4; m++)
#pragma unroll
    for (int n = 0; n < 4; n++) {
      const int col = bcol + wc * 64 + n * 16 + lr;
#pragma unroll
      for (int r = 0; r < 4; r++) {
        const int rowl = wr * 64 + m * 16 + hi * 4 + r;
        const long row = brow + rowl;
        float v = acc[m][n][r];
        float bv = 0.f;
#pragma unroll
        for (int e = 0; e < 6; e++) bv += CfT[e][rowl] * bias[(long)e * N + col];
        v += bv;
        v = elu1(v);
        outH[row * (long)ldo + col] = f2b(v);
      }
    }
}

// ================= 8-wave dense GEMM (encoder): R6-proven fine-phase schedule.
template<int KSTEPS>
__global__ __launch_bounds__(512, 2) void k_gemm8(
    const u16* __restrict__ A,
    const u16* __restrict__ WT,
    const float* __restrict__ bias,
    int N,
    u16* __restrict__ outH, int ldo)
{
  constexpr int KK = KSTEPS * BK;
  constexpr int T = KSTEPS;
  __shared__ __align__(16) u16 As[3][256][BK];
  __shared__ __align__(16) u16 Bs[3][128][BK];

  const int tid = threadIdx.x;
  const int lane = tid & 63, w = tid >> 6;
  const int wr = w >> 1, wc = w & 1;
  const int lin = blockIdx.x + blockIdx.y * gridDim.x;
  const int rb  = (lin & 7) * 4 + ((lin >> 3) & 3);
  const int cp  = lin >> 5;
  const int brow = rb * 256, bcol = cp * 128;
  const int lr = lane & 15, hi = lane >> 4;
  const int lk = hi * 8;
  const int xsw = (lr & 7) << 3;

  f32x4 acc[4][4];
#pragma unroll
  for (int m = 0; m < 4; m++)
#pragma unroll
    for (int n = 0; n < 4; n++)
#pragma unroll
      for (int r = 0; r < 4; r++) acc[m][n][r] = 0.f;

  const int srow = w * 8 + (lane >> 3);
  const int sdst = (lane & 7) * 8;
  const int ssrc = ((lane & 7) ^ ((lane >> 3) & 7)) * 8;
  const u16* Asrc = A + (long)(brow + srow) * KK + ssrc;
  const u16* Bsrc = WT + (long)(bcol + srow) * KK + ssrc;

  auto STAGE_H = [&](int t2, int buf, int h) {
    const u16* ap = Asrc + (long)t2 * BK;
    const u16* bp = Bsrc + (long)t2 * BK;
    GLDS(ap + (long)((h * 2 + 0) * 64) * KK, &As[buf][(h * 2 + 0) * 64 + srow][sdst]);
    GLDS(ap + (long)((h * 2 + 1) * 64) * KK, &As[buf][(h * 2 + 1) * 64 + srow][sdst]);
    GLDS(bp + (long)(h * 64) * KK,           &Bs[buf][h * 64 + srow][sdst]);
  };

  STAGE_H(0, 0, 0); STAGE_H(0, 0, 1);
  STAGE_H(1, 1, 0); STAGE_H(1, 1, 1);
  asm volatile("s_waitcnt vmcnt(6)" ::: "memory");
  asm volatile("s_barrier" ::: "memory");

  for (int t = 0; t < T; ++t) {
    const int cur = t % 3;
    const int nbuf = (t + 2) % 3;
    const bool do_stage = (t + 2 < T);

    { // phase 0
      short8 af[4], bfr[4];
      const int cc = lk ^ xsw;
#pragma unroll
      for (int m = 0; m < 4; m++)
        af[m] = *(const short8*)&As[cur][wr * 64 + m * 16 + lr][cc];
#pragma unroll
      for (int n = 0; n < 4; n++)
        bfr[n] = *(const short8*)&Bs[cur][wc * 64 + n * 16 + lr][cc];
      if (do_stage) STAGE_H(t + 2, nbuf, 0);
      asm volatile("s_barrier" ::: "memory");
      __builtin_amdgcn_s_setprio(1);
#pragma unroll
      for (int m = 0; m < 4; m++)
#pragma unroll
        for (int n = 0; n < 4; n++)
          acc[m][n] = __builtin_amdgcn_mfma_f32_16x16x32_bf16(af[m], bfr[n], acc[m][n], 0, 0, 0);
      __builtin_amdgcn_s_setprio(0);
      asm volatile("s_barrier" ::: "memory");
    }
    { // phase 1
      short8 af[4], bfr[4];
      const int cc = (32 + lk) ^ xsw;
#pragma unroll
      for (int m = 0; m < 4; m++)
        af[m] = *(const short8*)&As[cur][wr * 64 + m * 16 + lr][cc];
#pragma unroll
      for (int n = 0; n < 4; n++)
        bfr[n] = *(const short8*)&Bs[cur][wc * 64 + n * 16 + lr][cc];
      if (do_stage) STAGE_H(t + 2, nbuf, 1);
      asm volatile("s_barrier" ::: "memory");
      __builtin_amdgcn_s_setprio(1);
#pragma unroll
      for (int m = 0; m < 4; m++)
#pragma unroll
        for (int n = 0; n < 4; n++)
          acc[m][n] = __builtin_amdgcn_mfma_f32_16x16x32_bf16(af[m], bfr[n], acc[m][n], 0, 0, 0);
      __builtin_amdgcn_s_setprio(0);
      if (t + 1 < T) {
        if (do_stage) asm volatile("s_waitcnt vmcnt(6)" ::: "memory");
        else          asm volatile("s_waitcnt vmcnt(0)" ::: "memory");
      }
      asm volatile("s_barrier" ::: "memory");
    }
  }

#pragma unroll
  for (int m = 0; m < 4; m++)
#pragma unroll
    for (int n = 0; n < 4; n++) {
      const int col = bcol + wc * 64 + n * 16 + lr;
#pragma unroll
      for (int r = 0; r < 4; r++) {
        const int rowl = wr * 64 + m * 16 + hi * 4 + r;
        const long row = brow + rowl;
        float v = acc[m][n][r] + bias[col];
        v = elu1(v);
        outH[row * (long)ldo + col] = f2b(v);
      }
    }
}

// ================= k_m2: 4-wave co-tenant GEMM (+MoE), BM=64, BN=128, BK=64.
template<int KSTEPS, int E, bool MOE>
__global__ __launch_bounds__(256, 2) void k_m2(
    const u16* __restrict__ A,
    const u16* __restrict__ WT,
    const float* __restrict__ bias, const float* __restrict__ bias2,
    const float* __restrict__ coeff,
    int N,
    u16* __restrict__ outH, float* __restrict__ outF, float* __restrict__ outF2,
    int ldo, int splitcol, int act)
{
  constexpr int KK = KSTEPS * BK;
  constexpr int T = E * KSTEPS;
  __shared__ __align__(16) u16 As[3][64][BK];
  __shared__ __align__(16) u16 Bs[3][128][BK];
  __shared__ float Cf[MOE ? 64 : 1][8];

  const int tid = threadIdx.x;
  const int lane = tid & 63, w = tid >> 6;
  const int wr = w >> 1, wc = w & 1;
  const int brow = blockIdx.x * 64, bcol = blockIdx.y * 128;
  const int lr = lane & 15, hi = lane >> 4;
  const int lk = hi * 8;
  const int xsw = (lr & 7) << 3;

  if (MOE) {
    if (tid < 64) {
#pragma unroll
      for (int e2 = 0; e2 < 8; e2++)
        Cf[tid][e2] = (e2 < 6) ? coeff[(long)(brow + tid) * 6 + e2] : 0.f;
    }
    __syncthreads();
  }

  f32x4 acc[2][4];
#pragma unroll
  for (int m = 0; m < 2; m++)
#pragma unroll
    for (int n = 0; n < 4; n++)
#pragma unroll
      for (int r = 0; r < 4; r++) acc[m][n][r] = 0.f;
  f32x4 pacc[MOE ? 2 : 1][MOE ? 4 : 1];
  if constexpr (MOE) {
#pragma unroll
    for (int m = 0; m < 2; m++)
#pragma unroll
      for (int n = 0; n < 4; n++)
#pragma unroll
        for (int r = 0; r < 4; r++) pacc[m][n][r] = 0.f;
  }

  const int srow = w * 8 + (lane >> 3);
  const int sdst = (lane & 7) * 8;
  const int ssrc = ((lane & 7) ^ ((lane >> 3) & 7)) * 8;
  const u16* Asrc = A + (long)(brow + srow) * KK + ssrc;
  const u16* Bsrc = WT + (long)(bcol + srow) * KK + ssrc;

  auto STAGE_H = [&](int t2, int buf, int h) {
    const int e2 = (E == 1) ? 0 : (t2 / KSTEPS);
    int k2 = (E == 1) ? t2 : (t2 % KSTEPS);
    if (E > 1 && (e2 & 1)) k2 = KSTEPS - 1 - k2;
    const u16* ap = Asrc + (long)k2 * BK;
    const u16* bp = Bsrc + (long)e2 * ((long)N * KK) + (long)k2 * BK;
    GLDS(ap + (long)(h * 32) * KK,            &As[buf][h * 32 + srow][sdst]);
    GLDS(bp + (long)(h * 64) * KK,            &Bs[buf][h * 64 + srow][sdst]);
    GLDS(bp + (long)(h * 64 + 32) * KK,       &Bs[buf][h * 64 + 32 + srow][sdst]);
  };

  STAGE_H(0, 0, 0); STAGE_H(0, 0, 1);
  STAGE_H(1, 1, 0); STAGE_H(1, 1, 1);
  asm volatile("s_waitcnt vmcnt(6)" ::: "memory");
  asm volatile("s_barrier" ::: "memory");

  for (int t = 0; t < T; ++t) {
    const int cur = t % 3;
    const int nbuf = (t + 2) % 3;
    const bool do_stage = (t + 2 < T);

    { // phase 0
      short8 af[2], bfr[4];
      const int cc = lk ^ xsw;
#pragma unroll
      for (int m = 0; m < 2; m++)
        af[m] = *(const short8*)&As[cur][wr * 32 + m * 16 + lr][cc];
#pragma unroll
      for (int n = 0; n < 4; n++)
        bfr[n] = *(const short8*)&Bs[cur][wc * 64 + n * 16 + lr][cc];
      if (do_stage) STAGE_H(t + 2, nbuf, 0);
      asm volatile("s_barrier" ::: "memory");
      __builtin_amdgcn_s_setprio(1);
#pragma unroll
      for (int m = 0; m < 2; m++)
#pragma unroll
        for (int n = 0; n < 4; n++) {
          if constexpr (MOE)
            pacc[m][n] = __builtin_amdgcn_mfma_f32_16x16x32_bf16(af[m], bfr[n], pacc[m][n], 0, 0, 0);
          else
            acc[m][n] = __builtin_amdgcn_mfma_f32_16x16x32_bf16(af[m], bfr[n], acc[m][n], 0, 0, 0);
        }
      __builtin_amdgcn_s_setprio(0);
      asm volatile("s_barrier" ::: "memory");
    }
    { // phase 1
      short8 af[2], bfr[4];
      const int cc = (32 + lk) ^ xsw;
#pragma unroll
      for (int m = 0; m < 2; m++)
        af[m] = *(const short8*)&As[cur][wr * 32 + m * 16 + lr][cc];
#pragma unroll
      for (int n = 0; n < 4; n++)
        bfr[n] = *(const short8*)&Bs[cur][wc * 64 + n * 16 + lr][cc];
      if (do_stage) STAGE_H(t + 2, nbuf, 1);
      asm volatile("s_barrier" ::: "memory");
      __builtin_amdgcn_s_setprio(1);
#pragma unroll
      for (int m = 0; m < 2; m++)
#pragma unroll
        for (int n = 0; n < 4; n++) {
          if constexpr (MOE)
            pacc[m][n] = __builtin_amdgcn_mfma_f32_16x16x32_bf16(af[m], bfr[n], pacc[m][n], 0, 0, 0);
          else
            acc[m][n] = __builtin_amdgcn_mfma_f32_16x16x32_bf16(af[m], bfr[n], acc[m][n], 0, 0, 0);
        }
      __builtin_amdgcn_s_setprio(0);
      if (t + 1 < T) {
        if (do_stage) asm volatile("s_waitcnt vmcnt(6)" ::: "memory");
        else          asm volatile("s_waitcnt vmcnt(0)" ::: "memory");
      }
      asm volatile("s_barrier" ::: "memory");
    }

    if constexpr (MOE) {
      if ((t + 1) % KSTEPS == 0) {
        const int e = t / KSTEPS;
#pragma unroll
        for (int m = 0; m < 2; m++)
#pragma unroll
          for (int r = 0; r < 4; r++) {
            float c = Cf[wr * 32 + m * 16 + hi * 4 + r][e];
#pragma unroll
            for (int n = 0; n < 4; n++) acc[m][n][r] += c * pacc[m][n][r];
          }
        if (t + 1 < T) {
#pragma unroll
          for (int m = 0; m < 2; m++)
#pragma unroll
            for (int n = 0; n < 4; n++)
#pragma unroll
              for (int r = 0; r < 4; r++) pacc[m][n][r] = 0.f;
        }
      }
    }
  }

#pragma unroll
  for (int m = 0; m < 2; m++)
#pragma unroll
    for (int n = 0; n < 4; n++) {
      const int col = bcol + wc * 64 + n * 16 + lr;
      if (col >= N) continue;
#pragma unroll
      for (int r = 0; r < 4; r++) {
        const int rowl = wr * 32 + m * 16 + hi * 4 + r;
        const long row = brow + rowl;
        float v = acc[m][n][r];
        if constexpr (MOE) {
          float bv = 0.f;
#pragma unroll
          for (int e = 0; e < 6; e++) bv += Cf[rowl][e] * bias[(long)e * N + col];
          v += bv;
        } else {
          v += (col < splitcol) ? bias[col] : bias2[col - splitcol];
        }
        if (act) v = elu1(v);
        if (outH) outH[row * (long)ldo + col] = f2b(v);
        else if (col < splitcol) outF[row * (long)ldo + col] = v;
        else outF2[row * (long)ldo + (col - splitcol)] = v;
      }
    }
}

extern "C" void kernel_launch(void* const* d_in, const int* in_sizes, int n_in,
                              void* d_out, int out_size, void* d_ws, size_t ws_size,
                              hipStream_t stream) {
  (void)in_sizes; (void)out_size;
  if (n_in < 23) return;
  const float* x      = (const float*)d_in[0];
  const float* y      = (const float*)d_in[1];
  const float* eps    = (const float*)d_in[2];
  const float* enc_w0 = (const float*)d_in[3];
  const float* enc_b0 = (const float*)d_in[4];
  const float* enc_w1 = (const float*)d_in[5];
  const float* enc_b1 = (const float*)d_in[6];
  const float* mu_w   = (const float*)d_in[7];
  const float* mu_b   = (const float*)d_in[8];
  const float* lv_w   = (const float*)d_in[9];
  const float* lv_b   = (const float*)d_in[10];
  const float* g_w0   = (const float*)d_in[11];
  const float* g_b0   = (const float*)d_in[12];
  const float* g_w1   = (const float*)d_in[13];
  const float* g_b1   = (const float*)d_in[14];
  const float* g_w2   = (const float*)d_in[15];
  const float* g_b2   = (const float*)d_in[16];
  const float* exp_w0 = (const float*)d_in[17];
  const float* exp_b0 = (const float*)d_in[18];
  const float* exp_w1 = (const float*)d_in[19];
  const float* exp_b1 = (const float*)d_in[20];
  const float* exp_w2 = (const float*)d_in[21];
  const float* exp_b2 = (const float*)d_in[22];

  char* ws = (char*)d_ws;
  size_t off = 0;
  auto alloc = [&](size_t bytes) -> void* {
    void* p = ws + off; off += (bytes + 255) & ~(size_t)255; return p;
  };
  u16* A0     = (u16*)alloc((size_t)B_ * K0_ * 2);        // enc0 input [x|y|x]; later D1
  u16* A1     = (u16*)alloc((size_t)B_ * K1_ * 2);        // enc1 input [h1|x]; later D2
  u16* H2     = (u16*)alloc((size_t)B_ * H_ * 2);         // enc2 output; later G1/COEFF/ew2T
  u16* ZY     = (u16*)alloc((size_t)B_ * INP_ * 2);       // [z|y]; later ew1T
  u16* encw0T = (u16*)alloc((size_t)K0_ * H_ * 2);
  u16* encw1T = (u16*)alloc((size_t)K1_ * H_ * 2);
  u16* mulvT  = (u16*)alloc((size_t)256 * H_ * 2);
  u16* gw0T   = (u16*)alloc((size_t)GH_ * INP_ * 2);      // OOB-read safe: ew0T follows
  u16* ew0T   = (u16*)alloc((size_t)NE_ * H_ * INP_ * 2);
  if (ws_size < off) return;

  // aliases (lifetime-checked):
  u16* D1 = A0;                                  // A0 dead after enc0
  u16* D2 = A1;                                  // A1 dead after enc1
  float* G1    = (float*)H2;                     // H2 dead after mu/lv
  float* COEFF = (float*)((char*)H2 + (size_t)B_ * GH_ * 4);
  u16* ew2T = (u16*)((char*)H2 + (size_t)4 * 1024 * 1024);   // transposed after mu/lv
  u16* ew1T = ZY;                                            // transposed after moe0

  float* outO = (float*)d_out;                       // [B,256]
  float* muO  = outO + (size_t)B_ * IN_;             // [B,128]
  float* lvO  = muO + (size_t)B_ * LAT_;             // [B,128]

  // 1. all upfront transposes + concat prep (one launch)
  k_pre<<<67400, 256, 0, stream>>>(enc_w0, enc_w1, mu_w, lv_w, g_w0, exp_w0,
      x, y, encw0T, encw1T, mulvT, gw0T, ew0T, A0, A1);

  // 2-3. encoder (8-wave fine-phase)
  k_gemm8<K0_ / BK><<<dim3(32, 8), 512, 0, stream>>>(A0, encw0T, enc_b0, H_, A1, K1_);
  k_gemm8<K1_ / BK><<<dim3(32, 8), 512, 0, stream>>>(A1, encw1T, enc_b1, H_, H2, H_);

  // 4. mu / logvar (k_m2 dense, split f32 into d_out)
  k_m2<H_ / BK, 1, false><<<dim3(B_ / 64, 2), 256, 0, stream>>>(H2, mulvT,
      mu_b, lv_b, nullptr, 256, nullptr, muO, lvO, LAT_, LAT_, 0);

  // 5. exp_w2 transpose + z/ZY/D1/D2 (one launch)
  k_mid<<<38592, 256, 0, stream>>>(exp_w2, ew2T, muO, lvO, eps, y, ZY, D1, D2);

  // 6. gating g1 (k_m2 dense, N=64; OOB B-rows read into ew0T region - safe)
  k_m2<INP_ / BK, 1, false><<<dim3(B_ / 64, 1), 256, 0, stream>>>(ZY, gw0T,
      g_b0, g_b0, nullptr, GH_, nullptr, G1, nullptr, GH_, GH_, 1);
  // 7. gating tail + softmax
  k_gate<<<B_ / 256, 256, 0, stream>>>(G1, g_w1, g_b1, g_w2, g_b2, COEFF);

  // 8. decoder MoE layer 0: ZY -> D1[:,128:1152]  (kt-outer/expert-inner)
  k_moe8<INP_ / BK><<<dim3(32, 8), 512, 0, stream>>>(ZY, ew0T, exp_b0,
      COEFF, H_, D1 + LAT_, INP_);
  // 9. exp_w1 transpose into freed ZY space
  k_transpose<<<dim3(32, 36, NE_), dim3(32, 8), 0, stream>>>(exp_w1, ew1T, INP_, H_,
                                                    (long)INP_ * H_, (long)INP_ * H_);
  // 10. decoder MoE layer 1: D1 -> D2[:,128:1152]
  k_moe8<INP_ / BK><<<dim3(32, 8), 512, 0, stream>>>(D1, ew1T, exp_b1,
      COEFF, H_, D2 + LAT_, INP_);
  // 11. decoder MoE layer 2: D2 -> d_out [B,256] f32 (k_m2 MoE)
  k_m2<INP_ / BK, NE_, true><<<dim3(B_ / 64, 2), 256, 0, stream>>>(D2, ew2T,
      exp_b2, nullptr, COEFF, IN_, nullptr, outO, nullptr, IN_, IN_, 0);
}

// Round 10
// 731.532 us; speedup vs baseline: 1.0727x; 1.0727x over previous
//
#include <hip/hip_runtime.h>
#include <hip/hip_bf16.h>
#include <cstddef>

using u16 = unsigned short;
using short8 = __attribute__((ext_vector_type(8))) short;
using f32x4 = __attribute__((ext_vector_type(4))) float;

constexpr int B_   = 8192;
constexpr int IN_  = 256;
constexpr int COND_= 1024;
constexpr int H_   = 1024;
constexpr int LAT_ = 128;
constexpr int NE_  = 6;
constexpr int GH_  = 64;
constexpr int INP_ = 1152;   // LAT+COND == LAT+H
constexpr int K0_  = 1536;   // IN+COND+IN
constexpr int K1_  = 1280;   // H+IN

constexpr int BK = 64;       // K-step (128 B per LDS row)

typedef const __attribute__((address_space(1))) void gv_t;
typedef __attribute__((address_space(3))) void lv_t;
#define GLDS(g, l) __builtin_amdgcn_global_load_lds((gv_t*)(g), (lv_t*)(l), 16, 0, 0)

__device__ __forceinline__ u16 f2b(float f) {
  __hip_bfloat16 h = __float2bfloat16(f);
  return *reinterpret_cast<u16*>(&h);
}
__device__ __forceinline__ float elu1(float x) { return x > 0.f ? x : (__expf(x) - 1.f); }

// ---------------- transpose + f32->bf16 convert (used for ew1T only)
__global__ void k_transpose(const float* __restrict__ in, u16* __restrict__ out,
                            int R, int C, long inStride, long outStride) {
  __shared__ float t[32][33];
  const float* ip = in + (long)blockIdx.z * inStride;
  u16* op = out + (long)blockIdx.z * outStride;
  int c0 = blockIdx.x * 32, r0 = blockIdx.y * 32;
  int tx = threadIdx.x, ty = threadIdx.y; // 32x8
#pragma unroll
  for (int i = 0; i < 4; i++) {
    int r = r0 + ty + i * 8, c = c0 + tx;
    if (r < R && c < C) t[ty + i * 8][tx] = ip[(long)r * C + c];
  }
  __syncthreads();
#pragma unroll
  for (int i = 0; i < 4; i++) {
    int c = c0 + ty + i * 8, r = r0 + tx;
    if (r < R && c < C) op[(long)c * R + r] = f2b(t[tx][ty + i * 8]);
  }
}

// ---------------- k_pre: ALL upfront weight transposes + A0/A1 concat prep.
__global__ __launch_bounds__(256) void k_pre(
    const float* __restrict__ enc_w0, const float* __restrict__ enc_w1,
    const float* __restrict__ mu_w, const float* __restrict__ lv_w,
    const float* __restrict__ g_w0, const float* __restrict__ exp_w0,
    const float* __restrict__ x, const float* __restrict__ y,
    u16* __restrict__ encw0T, u16* __restrict__ encw1T, u16* __restrict__ mulvT,
    u16* __restrict__ gw0T, u16* __restrict__ ew0T,
    u16* __restrict__ A0, u16* __restrict__ A1)
{
  __shared__ float t[32][33];
  const int b = blockIdx.x;
  const int tid = threadIdx.x;
  const int tx = tid & 31, ty = tid >> 5;

  auto tr = [&](const float* in, u16* out, int R, int C, int bx, int by) {
    int c0 = bx * 32, r0 = by * 32;
#pragma unroll
    for (int i = 0; i < 4; i++) {
      int r = r0 + ty + i * 8, c = c0 + tx;
      if (r < R && c < C) t[ty + i * 8][tx] = in[(long)r * C + c];
    }
    __syncthreads();
#pragma unroll
    for (int i = 0; i < 4; i++) {
      int c = c0 + ty + i * 8, r = r0 + tx;
      if (r < R && c < C) out[(long)c * R + r] = f2b(t[tx][ty + i * 8]);
    }
  };

  if (b < 1536)       { tr(enc_w0, encw0T, K0_, H_, b & 31, b >> 5); }
  else if (b < 2816)  { int l = b - 1536; tr(enc_w1, encw1T, K1_, H_, l & 31, l >> 5); }
  else if (b < 2944)  { int l = b - 2816; tr(mu_w, mulvT, H_, LAT_, l & 3, l >> 2); }
  else if (b < 3072)  { int l = b - 2944; tr(lv_w, mulvT + (size_t)LAT_ * H_, H_, LAT_, l & 3, l >> 2); }
  else if (b < 3144)  { int l = b - 3072; tr(g_w0, gw0T, INP_, GH_, l & 1, l >> 1); }
  else if (b < 10056) {
    int l = b - 3144, e = l / 1152, r2 = l % 1152;
    tr(exp_w0 + (long)e * INP_ * H_, ew0T + (long)e * INP_ * H_, INP_, H_, r2 & 31, r2 >> 5);
  } else {
    long idx = (long)(b - 10056) * 256 + tid;
    long n0 = (long)B_ * K0_;
    if (idx < n0) {
      int bb = (int)(idx / K0_), c = (int)(idx % K0_);
      float v;
      if (c < IN_)              v = x[(long)bb * IN_ + c];
      else if (c < IN_ + COND_) v = y[(long)bb * COND_ + (c - IN_)];
      else                      v = x[(long)bb * IN_ + (c - IN_ - COND_)];
      A0[idx] = f2b(v);
    } else {
      long j = idx - n0;
      if (j < (long)B_ * IN_) {
        int bb = (int)(j / IN_), c = (int)(j % IN_);
        A1[(long)bb * K1_ + H_ + c] = f2b(x[(long)bb * IN_ + c]);
      }
    }
  }
}

// ---------------- k_mid: exp_w2 transpose (blocks [0,1728)) + z/ZY/D1/D2 fill
__global__ __launch_bounds__(256) void k_mid(
    const float* __restrict__ exp_w2, u16* __restrict__ ew2T,
    const float* __restrict__ mu, const float* __restrict__ lv,
    const float* __restrict__ eps, const float* __restrict__ y,
    u16* __restrict__ ZY, u16* __restrict__ D1, u16* __restrict__ D2)
{
  __shared__ float t[32][33];
  const int b = blockIdx.x;
  const int tid = threadIdx.x;
  if (b < 1728) {
    const int tx = tid & 31, ty = tid >> 5;
    int e = b / 288, r2 = b % 288;
    const float* in = exp_w2 + (long)e * INP_ * IN_;
    u16* out = ew2T + (long)e * INP_ * IN_;
    int c0 = (r2 & 7) * 32, r0 = (r2 >> 3) * 32;
#pragma unroll
    for (int i = 0; i < 4; i++) {
      int r = r0 + ty + i * 8, c = c0 + tx;
      if (r < INP_ && c < IN_) t[ty + i * 8][tx] = in[(long)r * IN_ + c];
    }
    __syncthreads();
#pragma unroll
    for (int i = 0; i < 4; i++) {
      int c = c0 + ty + i * 8, r = r0 + tx;
      if (r < INP_ && c < IN_) out[(long)c * INP_ + r] = f2b(t[tx][ty + i * 8]);
    }
  } else {
    long idx = (long)(b - 1728) * 256 + tid;
    if (idx >= (long)B_ * INP_) return;
    int bb = (int)(idx / INP_), c = (int)(idx % INP_);
    if (c < LAT_) {
      long o = (long)bb * LAT_ + c;
      float z = mu[o] + eps[o] * __expf(0.5f * lv[o]);
      u16 zb = f2b(z);
      ZY[idx] = zb; D1[idx] = zb; D2[idx] = zb;
    } else {
      ZY[idx] = f2b(y[(long)bb * COND_ + (c - LAT_)]);
    }
  }
}

// ---------------- gating tail
__global__ __launch_bounds__(256) void k_gate(const float* __restrict__ G1,
    const float* __restrict__ w1, const float* __restrict__ b1,
    const float* __restrict__ w2, const float* __restrict__ b2,
    float* __restrict__ coeff) {
  __shared__ float W1[64][65];
  __shared__ float W2[64][8];
  __shared__ float B1[64], B2[8];
  int tid = threadIdx.x;
  for (int i = tid; i < 64 * 64; i += 256) W1[i >> 6][i & 63] = w1[i];
  for (int i = tid; i < 64 * 6; i += 256) W2[i / 6][i % 6] = w2[i];
  if (tid < 64) B1[tid] = b1[tid];
  if (tid < 8)  B2[tid] = (tid < 6) ? b2[tid] : 0.f;
  __syncthreads();
  int row = blockIdx.x * 256 + tid;
  const float* gr = G1 + (long)row * GH_;
  float g[64];
#pragma unroll
  for (int i = 0; i < 16; i++) {
    float4 v = *(const float4*)(gr + i * 4);
    g[i*4] = v.x; g[i*4+1] = v.y; g[i*4+2] = v.z; g[i*4+3] = v.w;
  }
  float lg[6];
#pragma unroll
  for (int e = 0; e < 6; e++) lg[e] = B2[e];
  for (int n = 0; n < 64; n++) {
    float s = B1[n];
#pragma unroll
    for (int k = 0; k < 64; k++) s += g[k] * W1[k][n];
    s = elu1(s);
#pragma unroll
    for (int e = 0; e < 6; e++) lg[e] += s * W2[n][e];
  }
  float m = lg[0];
#pragma unroll
  for (int e = 1; e < 6; e++) m = fmaxf(m, lg[e]);
  float p[6], sum = 0.f;
#pragma unroll
  for (int e = 0; e < 6; e++) { p[e] = __expf(lg[e] - m); sum += p[e]; }
  float inv = 1.f / sum;
#pragma unroll
  for (int e = 0; e < 6; e++) coeff[(long)row * 6 + e] = p[e] * inv;
}

// ================= k_moe8: kt-outer / expert-inner MoE GEMM. BM=256, BN=128.
// A[kt] staged ONCE per kt (ring-2), fragments HELD IN REGISTERS across all 6
// expert steps; B[e][kt] streams (ring-3). Eager per-step merge. R9 erratum:
// __launch_bounds__(512,2) made the compiler cap VGPR at 128 -> 240MB scratch
// spill. Fix: plain (512) => cap 256 (block residency), need ~220, no spill.
template<int KSTEPS>
__global__ __launch_bounds__(512) void k_moe8(
    const u16* __restrict__ A,
    const u16* __restrict__ WT,
    const float* __restrict__ bias,     // [6][N]
    const float* __restrict__ coeff,    // [M][6]
    int N,
    u16* __restrict__ outH, int ldo)
{
  constexpr int KK = KSTEPS * BK;
  __shared__ __align__(16) u16 As[2][256][BK];
  __shared__ __align__(16) u16 Bs[3][128][BK];
  __shared__ float CfT[6][256];

  const int tid = threadIdx.x;
  const int lane = tid & 63, w = tid >> 6;       // 8 waves
  const int wr = w >> 1, wc = w & 1;             // 4 x 2
  const int lin = blockIdx.x + blockIdx.y * gridDim.x;
  const int rb  = (lin & 7) * 4 + ((lin >> 3) & 3);  // row-slab XCD swizzle
  const int cp  = lin >> 5;
  const int brow = rb * 256, bcol = cp * 128;
  const int lr = lane & 15, hi = lane >> 4;
  const int lk = hi * 8;
  const int xsw = (lr & 7) << 3;

  if (tid < 256) {
#pragma unroll
    for (int e = 0; e < 6; e++) CfT[e][tid] = coeff[(long)(brow + tid) * 6 + e];
  }
  __syncthreads();   // CfT visible; drains its loads before vmcnt counting

  f32x4 acc[4][4];
#pragma unroll
  for (int m = 0; m < 4; m++)
#pragma unroll
    for (int n = 0; n < 4; n++)
#pragma unroll
      for (int r = 0; r < 4; r++) acc[m][n][r] = 0.f;
  const f32x4 zf = {0.f, 0.f, 0.f, 0.f};
  f32x4 pacc[4][4];

  const int srow = w * 8 + (lane >> 3);
  const int sdst = (lane & 7) * 8;
  const int ssrc = ((lane & 7) ^ ((lane >> 3) & 7)) * 8;
  const u16* Asrc = A + (long)(brow + srow) * KK + ssrc;
  const u16* Bsrc = WT + (long)(bcol + srow) * KK + ssrc;

  auto STAGE_A = [&](int kt2, int abuf2) {       // 4 GLDS
    const u16* ap = Asrc + (long)kt2 * BK;
#pragma unroll
    for (int i = 0; i < 4; i++)
      GLDS(ap + (long)(i * 64) * KK, &As[abuf2][i * 64 + srow][sdst]);
  };
  auto STAGE_B = [&](int e2, int k2, int buf) {  // 2 GLDS
    const u16* bp = Bsrc + (long)e2 * ((long)N * KK) + (long)k2 * BK;
    GLDS(bp,                 &Bs[buf][srow][sdst]);
    GLDS(bp + (long)64 * KK, &Bs[buf][64 + srow][sdst]);
  };

  // prologue: A[0], B[e=0,kt=0], B[e=1,kt=0]; drain A+B0, keep B1 in flight
  STAGE_A(0, 0);
  STAGE_B(0, 0, 0);
  STAGE_B(1, 0, 1);
  asm volatile("s_waitcnt vmcnt(2)" ::: "memory");
  asm volatile("s_barrier" ::: "memory");

  short8 af[2][4];   // A fragments for both phases, held across 6 expert steps

  for (int kt = 0; kt < KSTEPS; ++kt) {
    const int abuf = kt & 1;
    const bool haveA = (kt + 1 < KSTEPS);
#pragma unroll
    for (int g = 0; g < 6; ++g) {              // g == expert index
      const int cur = g % 3;                   // (kt*6+g)%3 == g%3
      const int nbuf = (g + 2) % 3;
      const int e2 = (g + 2) % 6;              // staged step s+2 -> expert
      const int k2 = kt + (g >= 4 ? 1 : 0);    //                 -> K-chunk
      const bool stageB = (k2 < KSTEPS);

      { // ---------- phase 0 (kk = 0) ----------
        if (g == 0) {
#pragma unroll
          for (int p = 0; p < 2; p++)
#pragma unroll
            for (int m = 0; m < 4; m++)
              af[p][m] = *(const short8*)&As[abuf][wr * 64 + m * 16 + lr][(p * 32 + lk) ^ xsw];
        }
        short8 bfr[4];
        const int cc0 = lk ^ xsw;
#pragma unroll
        for (int n = 0; n < 4; n++)
          bfr[n] = *(const short8*)&Bs[cur][wc * 64 + n * 16 + lr][cc0];
        if (stageB) STAGE_B(e2, k2, nbuf);
        if (g == 2 && haveA) STAGE_A(kt + 1, abuf ^ 1);
        asm volatile("s_barrier" ::: "memory");
        __builtin_amdgcn_s_setprio(1);
#pragma unroll
        for (int m = 0; m < 4; m++)
#pragma unroll
          for (int n = 0; n < 4; n++)
            pacc[m][n] = __builtin_amdgcn_mfma_f32_16x16x32_bf16(af[0][m], bfr[n], zf, 0, 0, 0);
        __builtin_amdgcn_s_setprio(0);
        asm volatile("s_barrier" ::: "memory");
      }
      { // ---------- phase 1 (kk = 32) ----------
        short8 bfr[4];
        const int cc1 = (32 + lk) ^ xsw;
#pragma unroll
        for (int n = 0; n < 4; n++)
          bfr[n] = *(const short8*)&Bs[cur][wc * 64 + n * 16 + lr][cc1];
        asm volatile("s_barrier" ::: "memory");
        __builtin_amdgcn_s_setprio(1);
#pragma unroll
        for (int m = 0; m < 4; m++)
#pragma unroll
          for (int n = 0; n < 4; n++)
            pacc[m][n] = __builtin_amdgcn_mfma_f32_16x16x32_bf16(af[1][m], bfr[n], pacc[m][n], 0, 0, 0);
        __builtin_amdgcn_s_setprio(0);
        // end-of-step wait: next step's B landed; newer loads stay in flight
        if (stageB) {
          if ((g == 2 || g == 3) && haveA)
            asm volatile("s_waitcnt vmcnt(6)" ::: "memory");
          else
            asm volatile("s_waitcnt vmcnt(2)" ::: "memory");
        } else if (g == 4) {
          asm volatile("s_waitcnt vmcnt(0)" ::: "memory");
        }
        asm volatile("s_barrier" ::: "memory");
      }
      // ---------- eager merge: acc += c_g * pacc (cg read here, short-lived)
#pragma unroll
      for (int m = 0; m < 4; m++) {
        const float4 cg = *(const float4*)&CfT[g][wr * 64 + m * 16 + hi * 4];
#pragma unroll
        for (int r = 0; r < 4; r++) {
          const float c = ((const float*)&cg)[r];
#pragma unroll
          for (int n = 0; n < 4; n++) acc[m][n][r] += c * pacc[m][n][r];
        }
      }
    }
  }

  // epilogue
#pragma unroll
  for (int m = 0; m < 4; m++)
#pragma unroll
    for (int n = 0; n < 4; n++) {
      const int col = bcol + wc * 64 + n * 16 + lr;
#pragma unroll
      for (int r = 0; r < 4; r++) {
        const int rowl = wr * 64 + m * 16 + hi * 4 + r;
        const long row = brow + rowl;
        float v = acc[m][n][r];
        float bv = 0.f;
#pragma unroll
        for (int e = 0; e < 6; e++) bv += CfT[e][rowl] * bias[(long)e * N + col];
        v += bv;
        v = elu1(v);
        outH[row * (long)ldo + col] = f2b(v);
      }
    }
}

// ================= 8-wave dense GEMM (encoder): R6-proven fine-phase schedule.
template<int KSTEPS>
__global__ __launch_bounds__(512, 2) void k_gemm8(
    const u16* __restrict__ A,
    const u16* __restrict__ WT,
    const float* __restrict__ bias,
    int N,
    u16* __restrict__ outH, int ldo)
{
  constexpr int KK = KSTEPS * BK;
  constexpr int T = KSTEPS;
  __shared__ __align__(16) u16 As[3][256][BK];
  __shared__ __align__(16) u16 Bs[3][128][BK];

  const int tid = threadIdx.x;
  const int lane = tid & 63, w = tid >> 6;
  const int wr = w >> 1, wc = w & 1;
  const int lin = blockIdx.x + blockIdx.y * gridDim.x;
  const int rb  = (lin & 7) * 4 + ((lin >> 3) & 3);
  const int cp  = lin >> 5;
  const int brow = rb * 256, bcol = cp * 128;
  const int lr = lane & 15, hi = lane >> 4;
  const int lk = hi * 8;
  const int xsw = (lr & 7) << 3;

  f32x4 acc[4][4];
#pragma unroll
  for (int m = 0; m < 4; m++)
#pragma unroll
    for (int n = 0; n < 4; n++)
#pragma unroll
      for (int r = 0; r < 4; r++) acc[m][n][r] = 0.f;

  const int srow = w * 8 + (lane >> 3);
  const int sdst = (lane & 7) * 8;
  const int ssrc = ((lane & 7) ^ ((lane >> 3) & 7)) * 8;
  const u16* Asrc = A + (long)(brow + srow) * KK + ssrc;
  const u16* Bsrc = WT + (long)(bcol + srow) * KK + ssrc;

  auto STAGE_H = [&](int t2, int buf, int h) {
    const u16* ap = Asrc + (long)t2 * BK;
    const u16* bp = Bsrc + (long)t2 * BK;
    GLDS(ap + (long)((h * 2 + 0) * 64) * KK, &As[buf][(h * 2 + 0) * 64 + srow][sdst]);
    GLDS(ap + (long)((h * 2 + 1) * 64) * KK, &As[buf][(h * 2 + 1) * 64 + srow][sdst]);
    GLDS(bp + (long)(h * 64) * KK,           &Bs[buf][h * 64 + srow][sdst]);
  };

  STAGE_H(0, 0, 0); STAGE_H(0, 0, 1);
  STAGE_H(1, 1, 0); STAGE_H(1, 1, 1);
  asm volatile("s_waitcnt vmcnt(6)" ::: "memory");
  asm volatile("s_barrier" ::: "memory");

  for (int t = 0; t < T; ++t) {
    const int cur = t % 3;
    const int nbuf = (t + 2) % 3;
    const bool do_stage = (t + 2 < T);

    { // phase 0
      short8 af[4], bfr[4];
      const int cc = lk ^ xsw;
#pragma unroll
      for (int m = 0; m < 4; m++)
        af[m] = *(const short8*)&As[cur][wr * 64 + m * 16 + lr][cc];
#pragma unroll
      for (int n = 0; n < 4; n++)
        bfr[n] = *(const short8*)&Bs[cur][wc * 64 + n * 16 + lr][cc];
      if (do_stage) STAGE_H(t + 2, nbuf, 0);
      asm volatile("s_barrier" ::: "memory");
      __builtin_amdgcn_s_setprio(1);
#pragma unroll
      for (int m = 0; m < 4; m++)
#pragma unroll
        for (int n = 0; n < 4; n++)
          acc[m][n] = __builtin_amdgcn_mfma_f32_16x16x32_bf16(af[m], bfr[n], acc[m][n], 0, 0, 0);
      __builtin_amdgcn_s_setprio(0);
      asm volatile("s_barrier" ::: "memory");
    }
    { // phase 1
      short8 af[4], bfr[4];
      const int cc = (32 + lk) ^ xsw;
#pragma unroll
      for (int m = 0; m < 4; m++)
        af[m] = *(const short8*)&As[cur][wr * 64 + m * 16 + lr][cc];
#pragma unroll
      for (int n = 0; n < 4; n++)
        bfr[n] = *(const short8*)&Bs[cur][wc * 64 + n * 16 + lr][cc];
      if (do_stage) STAGE_H(t + 2, nbuf, 1);
      asm volatile("s_barrier" ::: "memory");
      __builtin_amdgcn_s_setprio(1);
#pragma unroll
      for (int m = 0; m < 4; m++)
#pragma unroll
        for (int n = 0; n < 4; n++)
          acc[m][n] = __builtin_amdgcn_mfma_f32_16x16x32_bf16(af[m], bfr[n], acc[m][n], 0, 0, 0);
      __builtin_amdgcn_s_setprio(0);
      if (t + 1 < T) {
        if (do_stage) asm volatile("s_waitcnt vmcnt(6)" ::: "memory");
        else          asm volatile("s_waitcnt vmcnt(0)" ::: "memory");
      }
      asm volatile("s_barrier" ::: "memory");
    }
  }

#pragma unroll
  for (int m = 0; m < 4; m++)
#pragma unroll
    for (int n = 0; n < 4; n++) {
      const int col = bcol + wc * 64 + n * 16 + lr;
#pragma unroll
      for (int r = 0; r < 4; r++) {
        const int rowl = wr * 64 + m * 16 + hi * 4 + r;
        const long row = brow + rowl;
        float v = acc[m][n][r] + bias[col];
        v = elu1(v);
        outH[row * (long)ldo + col] = f2b(v);
      }
    }
}

// ================= k_m2: 4-wave co-tenant GEMM (+MoE), BM=64, BN=128, BK=64.
template<int KSTEPS, int E, bool MOE>
__global__ __launch_bounds__(256, 2) void k_m2(
    const u16* __restrict__ A,
    const u16* __restrict__ WT,
    const float* __restrict__ bias, const float* __restrict__ bias2,
    const float* __restrict__ coeff,
    int N,
    u16* __restrict__ outH, float* __restrict__ outF, float* __restrict__ outF2,
    int ldo, int splitcol, int act)
{
  constexpr int KK = KSTEPS * BK;
  constexpr int T = E * KSTEPS;
  __shared__ __align__(16) u16 As[3][64][BK];
  __shared__ __align__(16) u16 Bs[3][128][BK];
  __shared__ float Cf[MOE ? 64 : 1][8];

  const int tid = threadIdx.x;
  const int lane = tid & 63, w = tid >> 6;
  const int wr = w >> 1, wc = w & 1;
  const int brow = blockIdx.x * 64, bcol = blockIdx.y * 128;
  const int lr = lane & 15, hi = lane >> 4;
  const int lk = hi * 8;
  const int xsw = (lr & 7) << 3;

  if (MOE) {
    if (tid < 64) {
#pragma unroll
      for (int e2 = 0; e2 < 8; e2++)
        Cf[tid][e2] = (e2 < 6) ? coeff[(long)(brow + tid) * 6 + e2] : 0.f;
    }
    __syncthreads();
  }

  f32x4 acc[2][4];
#pragma unroll
  for (int m = 0; m < 2; m++)
#pragma unroll
    for (int n = 0; n < 4; n++)
#pragma unroll
      for (int r = 0; r < 4; r++) acc[m][n][r] = 0.f;
  f32x4 pacc[MOE ? 2 : 1][MOE ? 4 : 1];
  if constexpr (MOE) {
#pragma unroll
    for (int m = 0; m < 2; m++)
#pragma unroll
      for (int n = 0; n < 4; n++)
#pragma unroll
        for (int r = 0; r < 4; r++) pacc[m][n][r] = 0.f;
  }

  const int srow = w * 8 + (lane >> 3);
  const int sdst = (lane & 7) * 8;
  const int ssrc = ((lane & 7) ^ ((lane >> 3) & 7)) * 8;
  const u16* Asrc = A + (long)(brow + srow) * KK + ssrc;
  const u16* Bsrc = WT + (long)(bcol + srow) * KK + ssrc;

  auto STAGE_H = [&](int t2, int buf, int h) {
    const int e2 = (E == 1) ? 0 : (t2 / KSTEPS);
    int k2 = (E == 1) ? t2 : (t2 % KSTEPS);
    if (E > 1 && (e2 & 1)) k2 = KSTEPS - 1 - k2;
    const u16* ap = Asrc + (long)k2 * BK;
    const u16* bp = Bsrc + (long)e2 * ((long)N * KK) + (long)k2 * BK;
    GLDS(ap + (long)(h * 32) * KK,            &As[buf][h * 32 + srow][sdst]);
    GLDS(bp + (long)(h * 64) * KK,            &Bs[buf][h * 64 + srow][sdst]);
    GLDS(bp + (long)(h * 64 + 32) * KK,       &Bs[buf][h * 64 + 32 + srow][sdst]);
  };

  STAGE_H(0, 0, 0); STAGE_H(0, 0, 1);
  STAGE_H(1, 1, 0); STAGE_H(1, 1, 1);
  asm volatile("s_waitcnt vmcnt(6)" ::: "memory");
  asm volatile("s_barrier" ::: "memory");

  for (int t = 0; t < T; ++t) {
    const int cur = t % 3;
    const int nbuf = (t + 2) % 3;
    const bool do_stage = (t + 2 < T);

    { // phase 0
      short8 af[2], bfr[4];
      const int cc = lk ^ xsw;
#pragma unroll
      for (int m = 0; m < 2; m++)
        af[m] = *(const short8*)&As[cur][wr * 32 + m * 16 + lr][cc];
#pragma unroll
      for (int n = 0; n < 4; n++)
        bfr[n] = *(const short8*)&Bs[cur][wc * 64 + n * 16 + lr][cc];
      if (do_stage) STAGE_H(t + 2, nbuf, 0);
      asm volatile("s_barrier" ::: "memory");
      __builtin_amdgcn_s_setprio(1);
#pragma unroll
      for (int m = 0; m < 2; m++)
#pragma unroll
        for (int n = 0; n < 4; n++) {
          if constexpr (MOE)
            pacc[m][n] = __builtin_amdgcn_mfma_f32_16x16x32_bf16(af[m], bfr[n], pacc[m][n], 0, 0, 0);
          else
            acc[m][n] = __builtin_amdgcn_mfma_f32_16x16x32_bf16(af[m], bfr[n], acc[m][n], 0, 0, 0);
        }
      __builtin_amdgcn_s_setprio(0);
      asm volatile("s_barrier" ::: "memory");
    }
    { // phase 1
      short8 af[2], bfr[4];
      const int cc = (32 + lk) ^ xsw;
#pragma unroll
      for (int m = 0; m < 2; m++)
        af[m] = *(const short8*)&As[cur][wr * 32 + m * 16 + lr][cc];
#pragma unroll
      for (int n = 0; n < 4; n++)
        bfr[n] = *(const short8*)&Bs[cur][wc * 64 + n * 16 + lr][cc];
      if (do_stage) STAGE_H(t + 2, nbuf, 1);
      asm volatile("s_barrier" ::: "memory");
      __builtin_amdgcn_s_setprio(1);
#pragma unroll
      for (int m = 0; m < 2; m++)
#pragma unroll
        for (int n = 0; n < 4; n++) {
          if constexpr (MOE)
            pacc[m][n] = __builtin_amdgcn_mfma_f32_16x16x32_bf16(af[m], bfr[n], pacc[m][n], 0, 0, 0);
          else
            acc[m][n] = __builtin_amdgcn_mfma_f32_16x16x32_bf16(af[m], bfr[n], acc[m][n], 0, 0, 0);
        }
      __builtin_amdgcn_s_setprio(0);
      if (t + 1 < T) {
        if (do_stage) asm volatile("s_waitcnt vmcnt(6)" ::: "memory");
        else          asm volatile("s_waitcnt vmcnt(0)" ::: "memory");
      }
      asm volatile("s_barrier" ::: "memory");
    }

    if constexpr (MOE) {
      if ((t + 1) % KSTEPS == 0) {
        const int e = t / KSTEPS;
#pragma unroll
        for (int m = 0; m < 2; m++)
#pragma unroll
          for (int r = 0; r < 4; r++) {
            float c = Cf[wr * 32 + m * 16 + hi * 4 + r][e];
#pragma unroll
            for (int n = 0; n < 4; n++) acc[m][n][r] += c * pacc[m][n][r];
          }
        if (t + 1 < T) {
#pragma unroll
          for (int m = 0; m < 2; m++)
#pragma unroll
            for (int n = 0; n < 4; n++)
#pragma unroll
              for (int r = 0; r < 4; r++) pacc[m][n][r] = 0.f;
        }
      }
    }
  }

#pragma unroll
  for (int m = 0; m < 2; m++)
#pragma unroll
    for (int n = 0; n < 4; n++) {
      const int col = bcol + wc * 64 + n * 16 + lr;
      if (col >= N) continue;
#pragma unroll
      for (int r = 0; r < 4; r++) {
        const int rowl = wr * 32 + m * 16 + hi * 4 + r;
        const long row = brow + rowl;
        float v = acc[m][n][r];
        if constexpr (MOE) {
          float bv = 0.f;
#pragma unroll
          for (int e = 0; e < 6; e++) bv += Cf[rowl][e] * bias[(long)e * N + col];
          v += bv;
        } else {
          v += (col < splitcol) ? bias[col] : bias2[col - splitcol];
        }
        if (act) v = elu1(v);
        if (outH) outH[row * (long)ldo + col] = f2b(v);
        else if (col < splitcol) outF[row * (long)ldo + col] = v;
        else outF2[row * (long)ldo + (col - splitcol)] = v;
      }
    }
}

extern "C" void kernel_launch(void* const* d_in, const int* in_sizes, int n_in,
                              void* d_out, int out_size, void* d_ws, size_t ws_size,
                              hipStream_t stream) {
  (void)in_sizes; (void)out_size;
  if (n_in < 23) return;
  const float* x      = (const float*)d_in[0];
  const float* y      = (const float*)d_in[1];
  const float* eps    = (const float*)d_in[2];
  const float* enc_w0 = (const float*)d_in[3];
  const float* enc_b0 = (const float*)d_in[4];
  const float* enc_w1 = (const float*)d_in[5];
  const float* enc_b1 = (const float*)d_in[6];
  const float* mu_w   = (const float*)d_in[7];
  const float* mu_b   = (const float*)d_in[8];
  const float* lv_w   = (const float*)d_in[9];
  const float* lv_b   = (const float*)d_in[10];
  const float* g_w0   = (const float*)d_in[11];
  const float* g_b0   = (const float*)d_in[12];
  const float* g_w1   = (const float*)d_in[13];
  const float* g_b1   = (const float*)d_in[14];
  const float* g_w2   = (const float*)d_in[15];
  const float* g_b2   = (const float*)d_in[16];
  const float* exp_w0 = (const float*)d_in[17];
  const float* exp_b0 = (const float*)d_in[18];
  const float* exp_w1 = (const float*)d_in[19];
  const float* exp_b1 = (const float*)d_in[20];
  const float* exp_w2 = (const float*)d_in[21];
  const float* exp_b2 = (const float*)d_in[22];

  char* ws = (char*)d_ws;
  size_t off = 0;
  auto alloc = [&](size_t bytes) -> void* {
    void* p = ws + off; off += (bytes + 255) & ~(size_t)255; return p;
  };
  u16* A0     = (u16*)alloc((size_t)B_ * K0_ * 2);        // enc0 input [x|y|x]; later D1
  u16* A1     = (u16*)alloc((size_t)B_ * K1_ * 2);        // enc1 input [h1|x]; later D2
  u16* H2     = (u16*)alloc((size_t)B_ * H_ * 2);         // enc2 output; later G1/COEFF/ew2T
  u16* ZY     = (u16*)alloc((size_t)B_ * INP_ * 2);       // [z|y]; later ew1T
  u16* encw0T = (u16*)alloc((size_t)K0_ * H_ * 2);
  u16* encw1T = (u16*)alloc((size_t)K1_ * H_ * 2);
  u16* mulvT  = (u16*)alloc((size_t)256 * H_ * 2);
  u16* gw0T   = (u16*)alloc((size_t)GH_ * INP_ * 2);      // OOB-read safe: ew0T follows
  u16* ew0T   = (u16*)alloc((size_t)NE_ * H_ * INP_ * 2);
  if (ws_size < off) return;

  // aliases (lifetime-checked):
  u16* D1 = A0;                                  // A0 dead after enc0
  u16* D2 = A1;                                  // A1 dead after enc1
  float* G1    = (float*)H2;                     // H2 dead after mu/lv
  float* COEFF = (float*)((char*)H2 + (size_t)B_ * GH_ * 4);
  u16* ew2T = (u16*)((char*)H2 + (size_t)4 * 1024 * 1024);   // transposed after mu/lv
  u16* ew1T = ZY;                                            // transposed after moe0

  float* outO = (float*)d_out;                       // [B,256]
  float* muO  = outO + (size_t)B_ * IN_;             // [B,128]
  float* lvO  = muO + (size_t)B_ * LAT_;             // [B,128]

  // 1. all upfront transposes + concat prep (one launch)
  k_pre<<<67400, 256, 0, stream>>>(enc_w0, enc_w1, mu_w, lv_w, g_w0, exp_w0,
      x, y, encw0T, encw1T, mulvT, gw0T, ew0T, A0, A1);

  // 2-3. encoder (8-wave fine-phase)
  k_gemm8<K0_ / BK><<<dim3(32, 8), 512, 0, stream>>>(A0, encw0T, enc_b0, H_, A1, K1_);
  k_gemm8<K1_ / BK><<<dim3(32, 8), 512, 0, stream>>>(A1, encw1T, enc_b1, H_, H2, H_);

  // 4. mu / logvar (k_m2 dense, split f32 into d_out)
  k_m2<H_ / BK, 1, false><<<dim3(B_ / 64, 2), 256, 0, stream>>>(H2, mulvT,
      mu_b, lv_b, nullptr, 256, nullptr, muO, lvO, LAT_, LAT_, 0);

  // 5. exp_w2 transpose + z/ZY/D1/D2 (one launch)
  k_mid<<<38592, 256, 0, stream>>>(exp_w2, ew2T, muO, lvO, eps, y, ZY, D1, D2);

  // 6. gating g1 (k_m2 dense, N=64; OOB B-rows read into ew0T region - safe)
  k_m2<INP_ / BK, 1, false><<<dim3(B_ / 64, 1), 256, 0, stream>>>(ZY, gw0T,
      g_b0, g_b0, nullptr, GH_, nullptr, G1, nullptr, GH_, GH_, 1);
  // 7. gating tail + softmax
  k_gate<<<B_ / 256, 256, 0, stream>>>(G1, g_w1, g_b1, g_w2, g_b2, COEFF);

  // 8. decoder MoE layer 0: ZY -> D1[:,128:1152]  (kt-outer/expert-inner)
  k_moe8<INP_ / BK><<<dim3(32, 8), 512, 0, stream>>>(ZY, ew0T, exp_b0,
      COEFF, H_, D1 + LAT_, INP_);
  // 9. exp_w1 transpose into freed ZY space
  k_transpose<<<dim3(32, 36, NE_), dim3(32, 8), 0, stream>>>(exp_w1, ew1T, INP_, H_,
                                                    (long)INP_ * H_, (long)INP_ * H_);
  // 10. decoder MoE layer 1: D1 -> D2[:,128:1152]
  k_moe8<INP_ / BK><<<dim3(32, 8), 512, 0, stream>>>(D1, ew1T, exp_b1,
      COEFF, H_, D2 + LAT_, INP_);
  // 11. decoder MoE layer 2: D2 -> d_out [B,256] f32 (k_m2 MoE)
  k_m2<INP_ / BK, NE_, true><<<dim3(B_ / 64, 2), 256, 0, stream>>>(D2, ew2T,
      exp_b2, nullptr, COEFF, IN_, nullptr, outO, nullptr, IN_, IN_, 0);
}

// Round 11
// 518.903 us; speedup vs baseline: 1.5122x; 1.4098x over previous
//
#include <hip/hip_runtime.h>
#include <hip/hip_bf16.h>
#include <cstddef>

using u16 = unsigned short;
using short8 = __attribute__((ext_vector_type(8))) short;
using f32x4 = __attribute__((ext_vector_type(4))) float;

constexpr int B_   = 8192;
constexpr int IN_  = 256;
constexpr int COND_= 1024;
constexpr int H_   = 1024;
constexpr int LAT_ = 128;
constexpr int NE_  = 6;
constexpr int GH_  = 64;
constexpr int INP_ = 1152;   // LAT+COND == LAT+H
constexpr int K0_  = 1536;   // IN+COND+IN
constexpr int K1_  = 1280;   // H+IN

constexpr int BK = 64;       // K-step (128 B per LDS row)

typedef const __attribute__((address_space(1))) void gv_t;
typedef __attribute__((address_space(3))) void lv_t;
#define GLDS(g, l) __builtin_amdgcn_global_load_lds((gv_t*)(g), (lv_t*)(l), 16, 0, 0)

__device__ __forceinline__ u16 f2b(float f) {
  __hip_bfloat16 h = __float2bfloat16(f);
  return *reinterpret_cast<u16*>(&h);
}
__device__ __forceinline__ ushort4 f2b4(float4 v) {
  ushort4 o;
  o.x = f2b(v.x); o.y = f2b(v.y); o.z = f2b(v.z); o.w = f2b(v.w);
  return o;
}
__device__ __forceinline__ float elu1(float x) { return x > 0.f ? x : (__expf(x) - 1.f); }

// ---------------- transpose + f32->bf16 convert (used for ew1T only)
__global__ void k_transpose(const float* __restrict__ in, u16* __restrict__ out,
                            int R, int C, long inStride, long outStride) {
  __shared__ float t[32][33];
  const float* ip = in + (long)blockIdx.z * inStride;
  u16* op = out + (long)blockIdx.z * outStride;
  int c0 = blockIdx.x * 32, r0 = blockIdx.y * 32;
  int tx = threadIdx.x, ty = threadIdx.y; // 32x8
#pragma unroll
  for (int i = 0; i < 4; i++) {
    int r = r0 + ty + i * 8, c = c0 + tx;
    if (r < R && c < C) t[ty + i * 8][tx] = ip[(long)r * C + c];
  }
  __syncthreads();
#pragma unroll
  for (int i = 0; i < 4; i++) {
    int c = c0 + ty + i * 8, r = r0 + tx;
    if (r < R && c < C) op[(long)c * R + r] = f2b(t[tx][ty + i * 8]);
  }
}

// ---------------- k_pre: ALL upfront weight transposes + A0/A1 concat prep.
// Transposes: blocks [0,10056). Prep (vec4): blocks [10056,24392).
__global__ __launch_bounds__(256) void k_pre(
    const float* __restrict__ enc_w0, const float* __restrict__ enc_w1,
    const float* __restrict__ mu_w, const float* __restrict__ lv_w,
    const float* __restrict__ g_w0, const float* __restrict__ exp_w0,
    const float* __restrict__ x, const float* __restrict__ y,
    u16* __restrict__ encw0T, u16* __restrict__ encw1T, u16* __restrict__ mulvT,
    u16* __restrict__ gw0T, u16* __restrict__ ew0T,
    u16* __restrict__ A0, u16* __restrict__ A1)
{
  __shared__ float t[32][33];
  const int b = blockIdx.x;
  const int tid = threadIdx.x;
  const int tx = tid & 31, ty = tid >> 5;

  auto tr = [&](const float* in, u16* out, int R, int C, int bx, int by) {
    int c0 = bx * 32, r0 = by * 32;
#pragma unroll
    for (int i = 0; i < 4; i++) {
      int r = r0 + ty + i * 8, c = c0 + tx;
      if (r < R && c < C) t[ty + i * 8][tx] = in[(long)r * C + c];
    }
    __syncthreads();
#pragma unroll
    for (int i = 0; i < 4; i++) {
      int c = c0 + ty + i * 8, r = r0 + tx;
      if (r < R && c < C) out[(long)c * R + r] = f2b(t[tx][ty + i * 8]);
    }
  };

  if (b < 1536)       { tr(enc_w0, encw0T, K0_, H_, b & 31, b >> 5); }
  else if (b < 2816)  { int l = b - 1536; tr(enc_w1, encw1T, K1_, H_, l & 31, l >> 5); }
  else if (b < 2944)  { int l = b - 2816; tr(mu_w, mulvT, H_, LAT_, l & 3, l >> 2); }
  else if (b < 3072)  { int l = b - 2944; tr(lv_w, mulvT + (size_t)LAT_ * H_, H_, LAT_, l & 3, l >> 2); }
  else if (b < 3144)  { int l = b - 3072; tr(g_w0, gw0T, INP_, GH_, l & 1, l >> 1); }
  else if (b < 10056) {
    int l = b - 3144, e = l / 1152, r2 = l % 1152;
    tr(exp_w0 + (long)e * INP_ * H_, ew0T + (long)e * INP_ * H_, INP_, H_, r2 & 31, r2 >> 5);
  } else {
    // vec4 prep: region boundaries (256,1280,1536) all %4==0 -> chunk region-pure
    long idx = (long)(b - 10056) * 256 + tid;
    long n0v = (long)B_ * K0_ / 4;
    if (idx < n0v) {
      long base = idx * 4;
      int bb = (int)(base / K0_), c = (int)(base % K0_);
      float4 v;
      if (c < IN_)              v = *(const float4*)&x[(long)bb * IN_ + c];
      else if (c < IN_ + COND_) v = *(const float4*)&y[(long)bb * COND_ + (c - IN_)];
      else                      v = *(const float4*)&x[(long)bb * IN_ + (c - IN_ - COND_)];
      *(ushort4*)&A0[base] = f2b4(v);
    } else {
      long j = idx - n0v;
      if (j < (long)B_ * IN_ / 4) {
        long base = j * 4;
        int bb = (int)(base / IN_), c = (int)(base % IN_);
        float4 v = *(const float4*)&x[(long)bb * IN_ + c];
        *(ushort4*)&A1[(long)bb * K1_ + H_ + c] = f2b4(v);
      }
    }
  }
}

// ---------------- k_mid: exp_w2 transpose (blocks [0,1728)) + z/ZY/D1/D2 fill
// Fill (vec4): blocks [1728,10944).
__global__ __launch_bounds__(256) void k_mid(
    const float* __restrict__ exp_w2, u16* __restrict__ ew2T,
    const float* __restrict__ mu, const float* __restrict__ lv,
    const float* __restrict__ eps, const float* __restrict__ y,
    u16* __restrict__ ZY, u16* __restrict__ D1, u16* __restrict__ D2)
{
  __shared__ float t[32][33];
  const int b = blockIdx.x;
  const int tid = threadIdx.x;
  if (b < 1728) {
    const int tx = tid & 31, ty = tid >> 5;
    int e = b / 288, r2 = b % 288;
    const float* in = exp_w2 + (long)e * INP_ * IN_;
    u16* out = ew2T + (long)e * INP_ * IN_;
    int c0 = (r2 & 7) * 32, r0 = (r2 >> 3) * 32;
#pragma unroll
    for (int i = 0; i < 4; i++) {
      int r = r0 + ty + i * 8, c = c0 + tx;
      if (r < INP_ && c < IN_) t[ty + i * 8][tx] = in[(long)r * IN_ + c];
    }
    __syncthreads();
#pragma unroll
    for (int i = 0; i < 4; i++) {
      int c = c0 + ty + i * 8, r = r0 + tx;
      if (r < INP_ && c < IN_) out[(long)c * INP_ + r] = f2b(t[tx][ty + i * 8]);
    }
  } else {
    // vec4 fill: LAT_=128 %4==0 -> chunk region-pure
    long idx = (long)(b - 1728) * 256 + tid;
    if (idx >= (long)B_ * INP_ / 4) return;
    long base = idx * 4;
    int bb = (int)(base / INP_), c = (int)(base % INP_);
    if (c < LAT_) {
      long o = (long)bb * LAT_ + c;
      float4 m = *(const float4*)&mu[o];
      float4 l = *(const float4*)&lv[o];
      float4 e4 = *(const float4*)&eps[o];
      float4 z;
      z.x = m.x + e4.x * __expf(0.5f * l.x);
      z.y = m.y + e4.y * __expf(0.5f * l.y);
      z.z = m.z + e4.z * __expf(0.5f * l.z);
      z.w = m.w + e4.w * __expf(0.5f * l.w);
      ushort4 zb = f2b4(z);
      *(ushort4*)&ZY[base] = zb;
      *(ushort4*)&D1[base] = zb;
      *(ushort4*)&D2[base] = zb;
    } else {
      float4 v = *(const float4*)&y[(long)bb * COND_ + (c - LAT_)];
      *(ushort4*)&ZY[base] = f2b4(v);
    }
  }
}

// ---------------- gating tail
__global__ __launch_bounds__(256) void k_gate(const float* __restrict__ G1,
    const float* __restrict__ w1, const float* __restrict__ b1,
    const float* __restrict__ w2, const float* __restrict__ b2,
    float* __restrict__ coeff) {
  __shared__ float W1[64][65];
  __shared__ float W2[64][8];
  __shared__ float B1[64], B2[8];
  int tid = threadIdx.x;
  for (int i = tid; i < 64 * 64; i += 256) W1[i >> 6][i & 63] = w1[i];
  for (int i = tid; i < 64 * 6; i += 256) W2[i / 6][i % 6] = w2[i];
  if (tid < 64) B1[tid] = b1[tid];
  if (tid < 8)  B2[tid] = (tid < 6) ? b2[tid] : 0.f;
  __syncthreads();
  int row = blockIdx.x * 256 + tid;
  const float* gr = G1 + (long)row * GH_;
  float g[64];
#pragma unroll
  for (int i = 0; i < 16; i++) {
    float4 v = *(const float4*)(gr + i * 4);
    g[i*4] = v.x; g[i*4+1] = v.y; g[i*4+2] = v.z; g[i*4+3] = v.w;
  }
  float lg[6];
#pragma unroll
  for (int e = 0; e < 6; e++) lg[e] = B2[e];
  for (int n = 0; n < 64; n++) {
    float s = B1[n];
#pragma unroll
    for (int k = 0; k < 64; k++) s += g[k] * W1[k][n];
    s = elu1(s);
#pragma unroll
    for (int e = 0; e < 6; e++) lg[e] += s * W2[n][e];
  }
  float m = lg[0];
#pragma unroll
  for (int e = 1; e < 6; e++) m = fmaxf(m, lg[e]);
  float p[6], sum = 0.f;
#pragma unroll
  for (int e = 0; e < 6; e++) { p[e] = __expf(lg[e] - m); sum += p[e]; }
  float inv = 1.f / sum;
#pragma unroll
  for (int e = 0; e < 6; e++) coeff[(long)row * 6 + e] = p[e] * inv;
}

// ================= 8-wave big-GEMM (+MoE): BM=256, BN=128, 512 threads.
// R6/R8-proven fine-phase schedule: per K-step 2 phases of
// {8x ds_read | 3 GLDS of tile t+2's half | s_barrier | setprio MFMA | s_barrier};
// vmcnt(6) once per step. 3-buffer ring, row-slab XCD swizzle, serpentine K.
// (R9/R10 erratum: kt-outer A-reuse variant spilled at 8 waves - abandoned.)
template<int KSTEPS, int E, bool MOE>
__global__ __launch_bounds__(512, 2) void k_gemm8(
    const u16* __restrict__ A,
    const u16* __restrict__ WT,
    const float* __restrict__ bias,     // MOE: [E][N]; dense: [N]
    const float* __restrict__ coeff,    // MOE: [M][6]
    int N,
    u16* __restrict__ outH, int ldo)
{
  constexpr int KK = KSTEPS * BK;
  constexpr int T = E * KSTEPS;
  __shared__ __align__(16) u16 As[3][256][BK];
  __shared__ __align__(16) u16 Bs[3][128][BK];
  __shared__ float Cf[MOE ? 256 : 1][8];

  const int tid = threadIdx.x;
  const int lane = tid & 63, w = tid >> 6;       // 8 waves
  const int wr = w >> 1, wc = w & 1;             // 4 x 2
  const int lin = blockIdx.x + blockIdx.y * gridDim.x;
  const int rb  = (lin & 7) * 4 + ((lin >> 3) & 3);  // row-slab XCD swizzle
  const int cp  = lin >> 5;
  const int brow = rb * 256, bcol = cp * 128;
  const int lr = lane & 15, hi = lane >> 4;
  const int lk = hi * 8;
  const int xsw = (lr & 7) << 3;

  if (MOE) {
    if (tid < 256) {
#pragma unroll
      for (int e2 = 0; e2 < 8; e2++)
        Cf[tid][e2] = (e2 < 6) ? coeff[(long)(brow + tid) * 6 + e2] : 0.f;
    }
    __syncthreads();
  }

  f32x4 acc[4][4];
#pragma unroll
  for (int m = 0; m < 4; m++)
#pragma unroll
    for (int n = 0; n < 4; n++)
#pragma unroll
      for (int r = 0; r < 4; r++) acc[m][n][r] = 0.f;
  f32x4 pacc[MOE ? 4 : 1][MOE ? 4 : 1];
  if constexpr (MOE) {
#pragma unroll
    for (int m = 0; m < 4; m++)
#pragma unroll
      for (int n = 0; n < 4; n++)
#pragma unroll
        for (int r = 0; r < 4; r++) pacc[m][n][r] = 0.f;
  }

  const int srow = w * 8 + (lane >> 3);
  const int sdst = (lane & 7) * 8;
  const int ssrc = ((lane & 7) ^ ((lane >> 3) & 7)) * 8;
  const u16* Asrc = A + (long)(brow + srow) * KK + ssrc;
  const u16* Bsrc = WT + (long)(bcol + srow) * KK + ssrc;

  auto STAGE_H = [&](int t2, int buf, int h) {
    const int e2 = (E == 1) ? 0 : (t2 / KSTEPS);
    int k2 = (E == 1) ? t2 : (t2 % KSTEPS);
    if (E > 1 && (e2 & 1)) k2 = KSTEPS - 1 - k2;   // serpentine K
    const u16* ap = Asrc + (long)k2 * BK;
    const u16* bp = Bsrc + (long)e2 * ((long)N * KK) + (long)k2 * BK;
    GLDS(ap + (long)((h * 2 + 0) * 64) * KK, &As[buf][(h * 2 + 0) * 64 + srow][sdst]);
    GLDS(ap + (long)((h * 2 + 1) * 64) * KK, &As[buf][(h * 2 + 1) * 64 + srow][sdst]);
    GLDS(bp + (long)(h * 64) * KK,           &Bs[buf][h * 64 + srow][sdst]);
  };

  STAGE_H(0, 0, 0); STAGE_H(0, 0, 1);
  STAGE_H(1, 1, 0); STAGE_H(1, 1, 1);
  asm volatile("s_waitcnt vmcnt(6)" ::: "memory");
  asm volatile("s_barrier" ::: "memory");

  for (int t = 0; t < T; ++t) {
    const int cur = t % 3;
    const int nbuf = (t + 2) % 3;
    const bool do_stage = (t + 2 < T);

    { // phase 0 (kk=0)
      short8 af[4], bfr[4];
      const int cc = lk ^ xsw;
#pragma unroll
      for (int m = 0; m < 4; m++)
        af[m] = *(const short8*)&As[cur][wr * 64 + m * 16 + lr][cc];
#pragma unroll
      for (int n = 0; n < 4; n++)
        bfr[n] = *(const short8*)&Bs[cur][wc * 64 + n * 16 + lr][cc];
      if (do_stage) STAGE_H(t + 2, nbuf, 0);
      asm volatile("s_barrier" ::: "memory");
      __builtin_amdgcn_s_setprio(1);
#pragma unroll
      for (int m = 0; m < 4; m++)
#pragma unroll
        for (int n = 0; n < 4; n++) {
          if constexpr (MOE)
            pacc[m][n] = __builtin_amdgcn_mfma_f32_16x16x32_bf16(af[m], bfr[n], pacc[m][n], 0, 0, 0);
          else
            acc[m][n] = __builtin_amdgcn_mfma_f32_16x16x32_bf16(af[m], bfr[n], acc[m][n], 0, 0, 0);
        }
      __builtin_amdgcn_s_setprio(0);
      asm volatile("s_barrier" ::: "memory");
    }

    { // phase 1 (kk=32)
      short8 af[4], bfr[4];
      const int cc = (32 + lk) ^ xsw;
#pragma unroll
      for (int m = 0; m < 4; m++)
        af[m] = *(const short8*)&As[cur][wr * 64 + m * 16 + lr][cc];
#pragma unroll
      for (int n = 0; n < 4; n++)
        bfr[n] = *(const short8*)&Bs[cur][wc * 64 + n * 16 + lr][cc];
      if (do_stage) STAGE_H(t + 2, nbuf, 1);
      asm volatile("s_barrier" ::: "memory");
      __builtin_amdgcn_s_setprio(1);
#pragma unroll
      for (int m = 0; m < 4; m++)
#pragma unroll
        for (int n = 0; n < 4; n++) {
          if constexpr (MOE)
            pacc[m][n] = __builtin_amdgcn_mfma_f32_16x16x32_bf16(af[m], bfr[n], pacc[m][n], 0, 0, 0);
          else
            acc[m][n] = __builtin_amdgcn_mfma_f32_16x16x32_bf16(af[m], bfr[n], acc[m][n], 0, 0, 0);
        }
      __builtin_amdgcn_s_setprio(0);
      if (t + 1 < T) {
        if (do_stage) asm volatile("s_waitcnt vmcnt(6)" ::: "memory");
        else          asm volatile("s_waitcnt vmcnt(0)" ::: "memory");
      }
      asm volatile("s_barrier" ::: "memory");
    }

    if constexpr (MOE) {
      if ((t + 1) % KSTEPS == 0) {
        const int e = t / KSTEPS;
#pragma unroll
        for (int m = 0; m < 4; m++)
#pragma unroll
          for (int r = 0; r < 4; r++) {
            float c = Cf[wr * 64 + m * 16 + hi * 4 + r][e];
#pragma unroll
            for (int n = 0; n < 4; n++) acc[m][n][r] += c * pacc[m][n][r];
          }
        if (t + 1 < T) {
#pragma unroll
          for (int m = 0; m < 4; m++)
#pragma unroll
            for (int n = 0; n < 4; n++)
#pragma unroll
              for (int r = 0; r < 4; r++) pacc[m][n][r] = 0.f;
        }
      }
    }
  }

#pragma unroll
  for (int m = 0; m < 4; m++)
#pragma unroll
    for (int n = 0; n < 4; n++) {
      const int col = bcol + wc * 64 + n * 16 + lr;
#pragma unroll
      for (int r = 0; r < 4; r++) {
        const int rowl = wr * 64 + m * 16 + hi * 4 + r;
        const long row = brow + rowl;
        float v = acc[m][n][r];
        if constexpr (MOE) {
          float bv = 0.f;
#pragma unroll
          for (int e = 0; e < 6; e++) bv += Cf[rowl][e] * bias[(long)e * N + col];
          v += bv;
        } else {
          v += bias[col];
        }
        v = elu1(v);
        outH[row * (long)ldo + col] = f2b(v);
      }
    }
}

// ================= k_m2: 4-wave co-tenant GEMM (+MoE), BM=64, BN=128, BK=64.
template<int KSTEPS, int E, bool MOE>
__global__ __launch_bounds__(256, 2) void k_m2(
    const u16* __restrict__ A,
    const u16* __restrict__ WT,
    const float* __restrict__ bias, const float* __restrict__ bias2,
    const float* __restrict__ coeff,
    int N,
    u16* __restrict__ outH, float* __restrict__ outF, float* __restrict__ outF2,
    int ldo, int splitcol, int act)
{
  constexpr int KK = KSTEPS * BK;
  constexpr int T = E * KSTEPS;
  __shared__ __align__(16) u16 As[3][64][BK];
  __shared__ __align__(16) u16 Bs[3][128][BK];
  __shared__ float Cf[MOE ? 64 : 1][8];

  const int tid = threadIdx.x;
  const int lane = tid & 63, w = tid >> 6;
  const int wr = w >> 1, wc = w & 1;
  const int brow = blockIdx.x * 64, bcol = blockIdx.y * 128;
  const int lr = lane & 15, hi = lane >> 4;
  const int lk = hi * 8;
  const int xsw = (lr & 7) << 3;

  if (MOE) {
    if (tid < 64) {
#pragma unroll
      for (int e2 = 0; e2 < 8; e2++)
        Cf[tid][e2] = (e2 < 6) ? coeff[(long)(brow + tid) * 6 + e2] : 0.f;
    }
    __syncthreads();
  }

  f32x4 acc[2][4];
#pragma unroll
  for (int m = 0; m < 2; m++)
#pragma unroll
    for (int n = 0; n < 4; n++)
#pragma unroll
      for (int r = 0; r < 4; r++) acc[m][n][r] = 0.f;
  f32x4 pacc[MOE ? 2 : 1][MOE ? 4 : 1];
  if constexpr (MOE) {
#pragma unroll
    for (int m = 0; m < 2; m++)
#pragma unroll
      for (int n = 0; n < 4; n++)
#pragma unroll
        for (int r = 0; r < 4; r++) pacc[m][n][r] = 0.f;
  }

  const int srow = w * 8 + (lane >> 3);
  const int sdst = (lane & 7) * 8;
  const int ssrc = ((lane & 7) ^ ((lane >> 3) & 7)) * 8;
  const u16* Asrc = A + (long)(brow + srow) * KK + ssrc;
  const u16* Bsrc = WT + (long)(bcol + srow) * KK + ssrc;

  auto STAGE_H = [&](int t2, int buf, int h) {
    const int e2 = (E == 1) ? 0 : (t2 / KSTEPS);
    int k2 = (E == 1) ? t2 : (t2 % KSTEPS);
    if (E > 1 && (e2 & 1)) k2 = KSTEPS - 1 - k2;
    const u16* ap = Asrc + (long)k2 * BK;
    const u16* bp = Bsrc + (long)e2 * ((long)N * KK) + (long)k2 * BK;
    GLDS(ap + (long)(h * 32) * KK,            &As[buf][h * 32 + srow][sdst]);
    GLDS(bp + (long)(h * 64) * KK,            &Bs[buf][h * 64 + srow][sdst]);
    GLDS(bp + (long)(h * 64 + 32) * KK,       &Bs[buf][h * 64 + 32 + srow][sdst]);
  };

  STAGE_H(0, 0, 0); STAGE_H(0, 0, 1);
  STAGE_H(1, 1, 0); STAGE_H(1, 1, 1);
  asm volatile("s_waitcnt vmcnt(6)" ::: "memory");
  asm volatile("s_barrier" ::: "memory");

  for (int t = 0; t < T; ++t) {
    const int cur = t % 3;
    const int nbuf = (t + 2) % 3;
    const bool do_stage = (t + 2 < T);

    { // phase 0
      short8 af[2], bfr[4];
      const int cc = lk ^ xsw;
#pragma unroll
      for (int m = 0; m < 2; m++)
        af[m] = *(const short8*)&As[cur][wr * 32 + m * 16 + lr][cc];
#pragma unroll
      for (int n = 0; n < 4; n++)
        bfr[n] = *(const short8*)&Bs[cur][wc * 64 + n * 16 + lr][cc];
      if (do_stage) STAGE_H(t + 2, nbuf, 0);
      asm volatile("s_barrier" ::: "memory");
      __builtin_amdgcn_s_setprio(1);
#pragma unroll
      for (int m = 0; m < 2; m++)
#pragma unroll
        for (int n = 0; n < 4; n++) {
          if constexpr (MOE)
            pacc[m][n] = __builtin_amdgcn_mfma_f32_16x16x32_bf16(af[m], bfr[n], pacc[m][n], 0, 0, 0);
          else
            acc[m][n] = __builtin_amdgcn_mfma_f32_16x16x32_bf16(af[m], bfr[n], acc[m][n], 0, 0, 0);
        }
      __builtin_amdgcn_s_setprio(0);
      asm volatile("s_barrier" ::: "memory");
    }
    { // phase 1
      short8 af[2], bfr[4];
      const int cc = (32 + lk) ^ xsw;
#pragma unroll
      for (int m = 0; m < 2; m++)
        af[m] = *(const short8*)&As[cur][wr * 32 + m * 16 + lr][cc];
#pragma unroll
      for (int n = 0; n < 4; n++)
        bfr[n] = *(const short8*)&Bs[cur][wc * 64 + n * 16 + lr][cc];
      if (do_stage) STAGE_H(t + 2, nbuf, 1);
      asm volatile("s_barrier" ::: "memory");
      __builtin_amdgcn_s_setprio(1);
#pragma unroll
      for (int m = 0; m < 2; m++)
#pragma unroll
        for (int n = 0; n < 4; n++) {
          if constexpr (MOE)
            pacc[m][n] = __builtin_amdgcn_mfma_f32_16x16x32_bf16(af[m], bfr[n], pacc[m][n], 0, 0, 0);
          else
            acc[m][n] = __builtin_amdgcn_mfma_f32_16x16x32_bf16(af[m], bfr[n], acc[m][n], 0, 0, 0);
        }
      __builtin_amdgcn_s_setprio(0);
      if (t + 1 < T) {
        if (do_stage) asm volatile("s_waitcnt vmcnt(6)" ::: "memory");
        else          asm volatile("s_waitcnt vmcnt(0)" ::: "memory");
      }
      asm volatile("s_barrier" ::: "memory");
    }

    if constexpr (MOE) {
      if ((t + 1) % KSTEPS == 0) {
        const int e = t / KSTEPS;
#pragma unroll
        for (int m = 0; m < 2; m++)
#pragma unroll
          for (int r = 0; r < 4; r++) {
            float c = Cf[wr * 32 + m * 16 + hi * 4 + r][e];
#pragma unroll
            for (int n = 0; n < 4; n++) acc[m][n][r] += c * pacc[m][n][r];
          }
        if (t + 1 < T) {
#pragma unroll
          for (int m = 0; m < 2; m++)
#pragma unroll
            for (int n = 0; n < 4; n++)
#pragma unroll
              for (int r = 0; r < 4; r++) pacc[m][n][r] = 0.f;
        }
      }
    }
  }

#pragma unroll
  for (int m = 0; m < 2; m++)
#pragma unroll
    for (int n = 0; n < 4; n++) {
      const int col = bcol + wc * 64 + n * 16 + lr;
      if (col >= N) continue;
#pragma unroll
      for (int r = 0; r < 4; r++) {
        const int rowl = wr * 32 + m * 16 + hi * 4 + r;
        const long row = brow + rowl;
        float v = acc[m][n][r];
        if constexpr (MOE) {
          float bv = 0.f;
#pragma unroll
          for (int e = 0; e < 6; e++) bv += Cf[rowl][e] * bias[(long)e * N + col];
          v += bv;
        } else {
          v += (col < splitcol) ? bias[col] : bias2[col - splitcol];
        }
        if (act) v = elu1(v);
        if (outH) outH[row * (long)ldo + col] = f2b(v);
        else if (col < splitcol) outF[row * (long)ldo + col] = v;
        else outF2[row * (long)ldo + (col - splitcol)] = v;
      }
    }
}

extern "C" void kernel_launch(void* const* d_in, const int* in_sizes, int n_in,
                              void* d_out, int out_size, void* d_ws, size_t ws_size,
                              hipStream_t stream) {
  (void)in_sizes; (void)out_size;
  if (n_in < 23) return;
  const float* x      = (const float*)d_in[0];
  const float* y      = (const float*)d_in[1];
  const float* eps    = (const float*)d_in[2];
  const float* enc_w0 = (const float*)d_in[3];
  const float* enc_b0 = (const float*)d_in[4];
  const float* enc_w1 = (const float*)d_in[5];
  const float* enc_b1 = (const float*)d_in[6];
  const float* mu_w   = (const float*)d_in[7];
  const float* mu_b   = (const float*)d_in[8];
  const float* lv_w   = (const float*)d_in[9];
  const float* lv_b   = (const float*)d_in[10];
  const float* g_w0   = (const float*)d_in[11];
  const float* g_b0   = (const float*)d_in[12];
  const float* g_w1   = (const float*)d_in[13];
  const float* g_b1   = (const float*)d_in[14];
  const float* g_w2   = (const float*)d_in[15];
  const float* g_b2   = (const float*)d_in[16];
  const float* exp_w0 = (const float*)d_in[17];
  const float* exp_b0 = (const float*)d_in[18];
  const float* exp_w1 = (const float*)d_in[19];
  const float* exp_b1 = (const float*)d_in[20];
  const float* exp_w2 = (const float*)d_in[21];
  const float* exp_b2 = (const float*)d_in[22];

  char* ws = (char*)d_ws;
  size_t off = 0;
  auto alloc = [&](size_t bytes) -> void* {
    void* p = ws + off; off += (bytes + 255) & ~(size_t)255; return p;
  };
  u16* A0     = (u16*)alloc((size_t)B_ * K0_ * 2);        // enc0 input [x|y|x]; later D1
  u16* A1     = (u16*)alloc((size_t)B_ * K1_ * 2);        // enc1 input [h1|x]; later D2
  u16* H2     = (u16*)alloc((size_t)B_ * H_ * 2);         // enc2 output; later G1/COEFF/ew2T
  u16* ZY     = (u16*)alloc((size_t)B_ * INP_ * 2);       // [z|y]; later ew1T
  u16* encw0T = (u16*)alloc((size_t)K0_ * H_ * 2);
  u16* encw1T = (u16*)alloc((size_t)K1_ * H_ * 2);
  u16* mulvT  = (u16*)alloc((size_t)256 * H_ * 2);
  u16* gw0T   = (u16*)alloc((size_t)GH_ * INP_ * 2);      // OOB-read safe: ew0T follows
  u16* ew0T   = (u16*)alloc((size_t)NE_ * H_ * INP_ * 2);
  if (ws_size < off) return;

  // aliases (lifetime-checked):
  u16* D1 = A0;                                  // A0 dead after enc0
  u16* D2 = A1;                                  // A1 dead after enc1
  float* G1    = (float*)H2;                     // H2 dead after mu/lv
  float* COEFF = (float*)((char*)H2 + (size_t)B_ * GH_ * 4);
  u16* ew2T = (u16*)((char*)H2 + (size_t)4 * 1024 * 1024);   // transposed after mu/lv
  u16* ew1T = ZY;                                            // transposed after moe0

  float* outO = (float*)d_out;                       // [B,256]
  float* muO  = outO + (size_t)B_ * IN_;             // [B,128]
  float* lvO  = muO + (size_t)B_ * LAT_;             // [B,128]

  // 1. all upfront transposes + concat prep (one launch; prep vec4)
  k_pre<<<24392, 256, 0, stream>>>(enc_w0, enc_w1, mu_w, lv_w, g_w0, exp_w0,
      x, y, encw0T, encw1T, mulvT, gw0T, ew0T, A0, A1);

  // 2-3. encoder (8-wave fine-phase, 256x128 tiles, grid 256 blocks)
  k_gemm8<K0_ / BK, 1, false><<<dim3(32, 8), 512, 0, stream>>>(A0, encw0T, enc_b0,
      nullptr, H_, A1, K1_);
  k_gemm8<K1_ / BK, 1, false><<<dim3(32, 8), 512, 0, stream>>>(A1, encw1T, enc_b1,
      nullptr, H_, H2, H_);

  // 4. mu / logvar (k_m2 dense, split f32 into d_out)
  k_m2<H_ / BK, 1, false><<<dim3(B_ / 64, 2), 256, 0, stream>>>(H2, mulvT,
      mu_b, lv_b, nullptr, 256, nullptr, muO, lvO, LAT_, LAT_, 0);

  // 5. exp_w2 transpose + z/ZY/D1/D2 (one launch; fill vec4)
  k_mid<<<10944, 256, 0, stream>>>(exp_w2, ew2T, muO, lvO, eps, y, ZY, D1, D2);

  // 6. gating g1 (k_m2 dense, N=64; OOB B-rows read into ew0T region - safe)
  k_m2<INP_ / BK, 1, false><<<dim3(B_ / 64, 1), 256, 0, stream>>>(ZY, gw0T,
      g_b0, g_b0, nullptr, GH_, nullptr, G1, nullptr, GH_, GH_, 1);
  // 7. gating tail + softmax
  k_gate<<<B_ / 256, 256, 0, stream>>>(G1, g_w1, g_b1, g_w2, g_b2, COEFF);

  // 8. decoder MoE layer 0: ZY -> D1[:,128:1152]
  k_gemm8<INP_ / BK, NE_, true><<<dim3(32, 8), 512, 0, stream>>>(ZY, ew0T, exp_b0,
      COEFF, H_, D1 + LAT_, INP_);
  // 9. exp_w1 transpose into freed ZY space
  k_transpose<<<dim3(32, 36, NE_), dim3(32, 8), 0, stream>>>(exp_w1, ew1T, INP_, H_,
                                                    (long)INP_ * H_, (long)INP_ * H_);
  // 10. decoder MoE layer 1: D1 -> D2[:,128:1152]
  k_gemm8<INP_ / BK, NE_, true><<<dim3(32, 8), 512, 0, stream>>>(D1, ew1T, exp_b1,
      COEFF, H_, D2 + LAT_, INP_);
  // 11. decoder MoE layer 2: D2 -> d_out [B,256] f32 (k_m2 MoE)
  k_m2<INP_ / BK, NE_, true><<<dim3(B_ / 64, 2), 256, 0, stream>>>(D2, ew2T,
      exp_b2, nullptr, COEFF, IN_, nullptr, outO, nullptr, IN_, IN_, 0);
}